// Round 16
// baseline (566.310 us; speedup 1.0000x reference)
//
#include <hip/hip_runtime.h>
#include <hip/hip_bf16.h>
#include <math.h>

// ---------- types ----------
typedef __attribute__((ext_vector_type(8)))  __bf16 bfrag;   // MFMA A/B operand (8 bf16)
typedef __attribute__((ext_vector_type(4)))  float  f32x4;
typedef __attribute__((ext_vector_type(16))) float  f32x16;  // 32x32 MFMA C/D
typedef __attribute__((ext_vector_type(8)))  short  s16x8;
typedef __attribute__((ext_vector_type(4)))  short  s16x4;
typedef __attribute__((ext_vector_type(2)))  unsigned u32x2;
typedef __attribute__((ext_vector_type(4)))  unsigned u32x4;

__device__ __forceinline__ short f2bf(float f) {
  return (short)__builtin_bit_cast(unsigned short, (__bf16)f);
}
__device__ __forceinline__ float bf2f(short s) {
  return (float)__builtin_bit_cast(__bf16, (unsigned short)s);
}
__device__ __forceinline__ unsigned cvtpk(float lo, float hi_) {
  unsigned r;
  asm("v_cvt_pk_bf16_f32 %0, %1, %2" : "=v"(r) : "v"(lo), "v"(hi_));
  return r;
}
__device__ __forceinline__ void gll16(const void* g, void* l) {
  __builtin_amdgcn_global_load_lds((const __attribute__((address_space(1))) void*)g,
                                   (__attribute__((address_space(3))) void*)l, 16, 0, 0);
}

#define SB() __builtin_amdgcn_sched_barrier(0)

// ---------- f32 -> bf16 converts (nontemporal input reads: read-once data) ----------
__global__ __launch_bounds__(256) void cvt_f32_bf16(const float* __restrict__ in,
                                                    short* __restrict__ out, int n4) {
  int i = blockIdx.x * 256 + threadIdx.x;
  if (i >= n4) return;
  f32x4 v = __builtin_nontemporal_load((const f32x4*)in + i);
  s16x4 o;
  o.x = f2bf(v.x); o.y = f2bf(v.y); o.z = f2bf(v.z); o.w = f2bf(v.w);
  ((s16x4*)out)[i] = o;
}

__global__ __launch_bounds__(256) void cvt4(const float* __restrict__ x,
                                            const float* __restrict__ wq,
                                            const float* __restrict__ wk,
                                            const float* __restrict__ wv,
                                            short* __restrict__ xb,
                                            short* __restrict__ wqb,
                                            short* __restrict__ wkb,
                                            short* __restrict__ wvb) {
  const int b = blockIdx.x;
  const float* in; short* out; int base;
  if (b < 16384)      { in = x;  out = xb;  base = 0; }
  else if (b < 32768) { in = wq; out = wqb; base = 16384 * 256; }
  else if (b < 36864) { in = wk; out = wkb; base = 32768 * 256; }
  else                { in = wv; out = wvb; base = 36864 * 256; }
  const int idx = b * 256 + threadIdx.x - base;
  f32x4 v = __builtin_nontemporal_load((const f32x4*)in + idx);
  s16x4 o;
  o.x = f2bf(v.x); o.y = f2bf(v.y); o.z = f2bf(v.z); o.w = f2bf(v.w);
  ((s16x4*)out)[idx] = o;
}

// ---------- shared staging macro (half-tile = 128 rows x 64 cols, 2 gll16/thr) ----------
#define STG_(OP, OPs, boff, bb, hh, kt_, Kd)                                     \
  do {                                                                           \
    _Pragma("unroll")                                                            \
    for (int s = 0; s < 2; ++s)                                                  \
      gll16(OP + (size_t)(boff + (hh) * 128 + s * 64 + r0) * Kd + (kt_) * 64 + csrc * 8, \
            (char*)OPs[bb] + ((hh) * 128 + s * 64 + wid * 8) * 128);             \
  } while (0)

// ---------- GEMM 128x256 (QKV) + fused RoPE + fused V-transpose ----------
// r15 skeleton + PIPELINED LDS READS: all 16 frag reads issued up front
// (order-pinned A8,Blo4 | Bhi4), counted lgkmcnt(4)/lgkmcnt(0) before the two
// MFMA quads so Bhi's reads drain DURING quad0's MFMA (read/MFMA overlap).
// Barrier skeleton / stage slots / vmcnt ledger identical to r15 (WAR/RAW
// proofs carry over: staged regions' readers drain at the counted wait >=1
// barrier before the overwrite).
template<bool ROPE>
__global__ __launch_bounds__(512) void gemm128n(const short* __restrict__ A,
                                                const short* __restrict__ B,
                                                short* __restrict__ C,
                                                short* __restrict__ vt,
                                                int M, int N, int K, int NBX,
                                                const float* __restrict__ fcos,
                                                const float* __restrict__ fsin) {
  __shared__ __align__(16) short As[2][128 * 64];
  __shared__ __align__(16) short Bs[2][256 * 64];
  const int tid = threadIdx.x, lane = tid & 63, wid = tid >> 6;
  const int lr = lane & 15, lg = lane >> 4;
  const int wm = wid >> 2, wn = wid & 3;
  const int orig = blockIdx.x;
  const int xc = orig & 7, o8 = orig >> 3;
  const int s8 = o8 >> 5, t8 = o8 & 31;
  const int bmi = ((xc >> 1) << 3) + (t8 >> 2);
  const int bni = (xc & 1) * (NBX >> 1) + (s8 << 2) + (t8 & 3);
  const int bm = bmi << 7, bn = bni << 8;
  const int NT = K >> 6;
  const int r0 = tid >> 3;
  const int c0 = tid & 7;
  const int csrc = c0 ^ (r0 & 7);

  int ch[2];
#pragma unroll
  for (int ks = 0; ks < 2; ++ks) ch[ks] = (((ks << 2) | lg) ^ (lr & 7)) << 4;
  const int aoff  = (wm * 64 + lr) * 128;
  const int boff2 = (wn * 32 + lr) * 128;

#define RD_A(dst, bb)                                                            \
  do {                                                                           \
    const char* ab = (const char*)As[bb] + aoff;                                 \
    _Pragma("unroll") for (int i = 0; i < 4; ++i)                                \
      _Pragma("unroll") for (int ks = 0; ks < 2; ++ks)                           \
        dst[i][ks] = *(const bfrag*)(ab + i * 2048 + ch[ks]);                    \
  } while (0)
#define RD_B(dst, bb, jh)                                                        \
  do {                                                                           \
    const char* bp = (const char*)Bs[bb] + boff2 + (jh) * 16384;                 \
    _Pragma("unroll") for (int j = 0; j < 2; ++j)                                \
      _Pragma("unroll") for (int ks = 0; ks < 2; ++ks)                           \
        dst[j][ks] = *(const bfrag*)(bp + j * 2048 + ch[ks]);                    \
  } while (0)
#define MFMA16(af, bf, jh)                                                       \
  do {                                                                           \
    __builtin_amdgcn_s_setprio(1);                                               \
    _Pragma("unroll") for (int ks = 0; ks < 2; ++ks)                             \
      _Pragma("unroll") for (int i = 0; i < 4; ++i)                              \
        _Pragma("unroll") for (int j = 0; j < 2; ++j)                            \
          acc[i][(jh) * 2 + j] = __builtin_amdgcn_mfma_f32_16x16x32_bf16(        \
              af[i][ks], bf[j][ks], acc[i][(jh) * 2 + j], 0, 0, 0);              \
    __builtin_amdgcn_s_setprio(0);                                               \
  } while (0)

  STG_(A, As, bm, 0, 0, 0, K);
  STG_(B, Bs, bn, 0, 0, 0, K);
  STG_(B, Bs, bn, 0, 1, 0, K);
  if (NT > 1) {
    STG_(A, As, bm, 1, 0, 1, K);
    STG_(B, Bs, bn, 1, 0, 1, K);
    asm volatile("s_waitcnt vmcnt(4)" ::: "memory");
  } else {
    asm volatile("s_waitcnt vmcnt(0)" ::: "memory");
  }
  __builtin_amdgcn_s_barrier();
  SB();

  f32x4 acc[4][4] = {};
  bfrag a_[4][2], b_lo[2][2], b_hi[2][2];

  for (int kt = 0; kt < NT; ++kt) {
    const int b = kt & 1;
    // ---- all 16 frag reads up front (pinned order: A8+Blo4 | Bhi4) ----
    RD_A(a_, b);
    RD_B(b_lo, b, 0);
    SB();
    RD_B(b_hi, b, 1);
    SB();
    if (kt + 1 < NT) STG_(B, Bs, bn, b ^ 1, 1, kt + 1, K);
    asm volatile("s_waitcnt lgkmcnt(4)" ::: "memory");  // A+Blo done; Bhi in flight
    SB();
    MFMA16(a_, b_lo, 0);
    __builtin_amdgcn_s_barrier();          // mid: all waves' A/Blo reads drained
    SB();
    if (kt + 2 < NT) {
      STG_(A, As, bm, b, 0, kt + 2, K);
      STG_(B, Bs, bn, b, 0, kt + 2, K);
    }
    asm volatile("s_waitcnt lgkmcnt(0)" ::: "memory");
    SB();
    MFMA16(a_, b_hi, 1);
    if (kt + 1 < NT) {
      if (kt + 2 < NT) asm volatile("s_waitcnt vmcnt(4)" ::: "memory");
      else             asm volatile("s_waitcnt vmcnt(0)" ::: "memory");
      __builtin_amdgcn_s_barrier();
      SB();
    }
  }
#undef RD_A
#undef RD_B
#undef MFMA16
  // ---- epilogue: RoPE (Q/K) | transposed-V | plain ----
  const int rb = bm + wm * 64 + lg * 4, cb = bn + wn * 32 + lr;
  if (ROPE && bn < 5120) {
    const bool odd = (lr & 1) != 0;
#pragma unroll
    for (int j = 0; j < 2; ++j) {
      const int iidx = (wn * 32 + j * 16 + lr) >> 1;
#pragma unroll
      for (int i = 0; i < 4; ++i)
#pragma unroll
        for (int r = 0; r < 4; ++r) {
          const int row = rb + i * 16 + r;
          const int sp = row & 2047;
          const float c  = fcos[sp * 64 + iidx];
          const float sn = fsin[sp * 64 + iidx];
#pragma unroll
          for (int jh = 0; jh < 2; ++jh) {
            float own = acc[i][jh * 2 + j][r];
            float par = __shfl_xor(own, 1, 64);
            float out = odd ? (par * sn + own * c) : (own * c - par * sn);
            C[(size_t)row * N + (cb + jh * 128 + j * 16)] = f2bf(out);
          }
        }
    }
  } else if (ROPE) {
    // V block: write transposed into vt[b][kvh][d][2048]; skip qkv write.
#pragma unroll
    for (int jh = 0; jh < 2; ++jh)
#pragma unroll
      for (int j = 0; j < 2; ++j) {
        const int vcol = cb + jh * 128 + j * 16 - 5120;   // 0..1023
        const int kvh = vcol >> 7, d = vcol & 127;
#pragma unroll
        for (int i = 0; i < 4; ++i) {
          const int row0 = rb + i * 16;                   // 4 consecutive tokens
          const int bb = row0 >> 11, s0 = row0 & 2047;
          s16x4 v;
#pragma unroll
          for (int r = 0; r < 4; ++r) v[r] = f2bf(acc[i][jh * 2 + j][r]);
          *(s16x4*)(vt + (size_t)((bb * 8 + kvh) * 128 + d) * 2048 + s0) = v;
        }
      }
  } else {
#pragma unroll
    for (int i = 0; i < 4; ++i)
#pragma unroll
      for (int jh = 0; jh < 2; ++jh)
#pragma unroll
        for (int j = 0; j < 2; ++j)
#pragma unroll
          for (int r = 0; r < 4; ++r)
            C[(size_t)(rb + i * 16 + r) * N + (cb + jh * 128 + j * 16)] =
                f2bf(acc[i][jh * 2 + j][r]);
  }
}

// ---------- GEMM 256x256, BK=64, 8-phase (out-proj) + pipelined LDS reads ----------
// All 24 frag reads of a K-tile issued at its first phase (pinned groups
// A8(ih0)+B4lo | B4hi | A8(ih1)); counted lgkmcnt 12/8/0 before the quads.
// Stage slots / barriers / vmcnt identical to r15.
template<bool BF16OUT>
__global__ __launch_bounds__(512) void gemm256p(const short* __restrict__ A,
                                                const short* __restrict__ B,
                                                void* __restrict__ Cv,
                                                int M, int N, int K, int NBX) {
  __shared__ __align__(16) short As[2][256 * 64];   // 64 KB
  __shared__ __align__(16) short Bs[2][256 * 64];   // 64 KB
  const int tid = threadIdx.x, lane = tid & 63, wid = tid >> 6;
  const int lr = lane & 15, lg = lane >> 4;
  const int wm = wid >> 2, wn = wid & 3;
  const int orig = blockIdx.x;
  const int xc = orig & 7, o8 = orig >> 3;
  const int bmi = ((xc >> 1) << 2) + (o8 & 3);
  const int bni = (xc & 1) * (NBX >> 1) + (o8 >> 2);
  const int bm = bmi << 8, bn = bni << 8;
  const int NT = K >> 6;
  const int r0 = tid >> 3;
  const int c0 = tid & 7;
  const int csrc = c0 ^ (r0 & 7);

  int ch[2];
#pragma unroll
  for (int ks = 0; ks < 2; ++ks) ch[ks] = (((ks << 2) | lg) ^ (lr & 7)) << 4;
  const int aoff = (wm * 128 + lr) * 128;
  const int boff = (wn * 64 + lr) * 128;

#define RD_A8(dst, bb, ih)                                                       \
  do {                                                                           \
    const char* ab = (const char*)As[bb] + aoff + (ih) * 8192;                   \
    _Pragma("unroll") for (int i = 0; i < 4; ++i)                                \
      _Pragma("unroll") for (int ks = 0; ks < 2; ++ks)                           \
        dst[i][ks] = *(const bfrag*)(ab + i * 2048 + ch[ks]);                    \
  } while (0)
#define RD_B4(dst, bb, jh)                                                       \
  do {                                                                           \
    const char* bp = (const char*)Bs[bb] + boff + (jh) * 4096;                   \
    _Pragma("unroll") for (int j = 0; j < 2; ++j)                                \
      _Pragma("unroll") for (int ks = 0; ks < 2; ++ks)                           \
        dst[j][ks] = *(const bfrag*)(bp + j * 2048 + ch[ks]);                    \
  } while (0)
#define QUAD(af, bf, ih, jh)                                                     \
  do {                                                                           \
    __builtin_amdgcn_s_setprio(1);                                               \
    _Pragma("unroll") for (int ks = 0; ks < 2; ++ks)                             \
      _Pragma("unroll") for (int i = 0; i < 4; ++i)                              \
        _Pragma("unroll") for (int j = 0; j < 2; ++j)                            \
          acc[(ih) * 4 + i][(jh) * 2 + j] = __builtin_amdgcn_mfma_f32_16x16x32_bf16( \
              af[i][ks], bf[j][ks], acc[(ih) * 4 + i][(jh) * 2 + j], 0, 0, 0);   \
    __builtin_amdgcn_s_setprio(0);                                               \
  } while (0)
#define BARRIER() do { __builtin_amdgcn_s_barrier(); SB(); } while (0)
#define RDALL(bb)                                                                \
  do {                                                                           \
    RD_A8(a0_, bb, 0);                                                           \
    RD_B4(b_lo, bb, 0);                                                          \
    SB();                                                                        \
    RD_B4(b_hi, bb, 1);                                                          \
    SB();                                                                        \
    RD_A8(a1_, bb, 1);                                                           \
    SB();                                                                        \
  } while (0)

  STG_(A, As, bm, 0, 0, 0, K); STG_(A, As, bm, 0, 1, 0, K);
  STG_(B, Bs, bn, 0, 0, 0, K); STG_(B, Bs, bn, 0, 1, 0, K);
  STG_(B, Bs, bn, 1, 0, 1, K); STG_(B, Bs, bn, 1, 1, 1, K);
  asm volatile("s_waitcnt vmcnt(4)" ::: "memory");
  BARRIER();

  f32x4 acc[8][4] = {};
  bfrag a0_[4][2], a1_[4][2], b_lo[2][2], b_hi[2][2];
  const int NI = NT >> 1;

  for (int it = 0; it < NI; ++it) {
    const int O  = 2 * it + 1;
    int E2 = 2 * it + 2; if (E2 >= NT) E2 = 0;
    int O2 = 2 * it + 3; if (O2 >= NT) O2 = 0;
    // ---- g0: all tile-E reads; stage A-h0(O)->buf1 ----
    RDALL(0);
    STG_(A, As, bm, 1, 0, O, K);
    BARRIER();
    asm volatile("s_waitcnt lgkmcnt(12)" ::: "memory");  // a0+b_lo done
    SB();
    QUAD(a0_, b_lo, 0, 0);
    BARRIER();
    // ---- g1 ----
    STG_(A, As, bm, 1, 1, O, K);
    BARRIER();
    asm volatile("s_waitcnt lgkmcnt(8)" ::: "memory");   // +b_hi done
    SB();
    QUAD(a0_, b_hi, 0, 1);
    BARRIER();
    // ---- g2 ----
    STG_(B, Bs, bn, 0, 0, E2, K);
    BARRIER();
    asm volatile("s_waitcnt lgkmcnt(0)" ::: "memory");   // +a1 done
    SB();
    QUAD(a1_, b_hi, 1, 1);
    BARRIER();
    // ---- g3 ----
    STG_(B, Bs, bn, 0, 1, E2, K);
    asm volatile("s_waitcnt vmcnt(4)" ::: "memory");     // tile O landed
    BARRIER();
    QUAD(a1_, b_lo, 1, 0);
    BARRIER();
    // ---- g4: all tile-O reads; stage A-h0(E2)->buf0 ----
    RDALL(1);
    STG_(A, As, bm, 0, 0, E2, K);
    BARRIER();
    asm volatile("s_waitcnt lgkmcnt(12)" ::: "memory");
    SB();
    QUAD(a0_, b_lo, 0, 0);
    BARRIER();
    // ---- g5 ----
    STG_(A, As, bm, 0, 1, E2, K);
    BARRIER();
    asm volatile("s_waitcnt lgkmcnt(8)" ::: "memory");
    SB();
    QUAD(a0_, b_hi, 0, 1);
    BARRIER();
    // ---- g6 ----
    STG_(B, Bs, bn, 1, 0, O2, K);
    BARRIER();
    asm volatile("s_waitcnt lgkmcnt(0)" ::: "memory");
    SB();
    QUAD(a1_, b_hi, 1, 1);
    BARRIER();
    // ---- g7 ----
    STG_(B, Bs, bn, 1, 1, O2, K);
    asm volatile("s_waitcnt vmcnt(4)" ::: "memory");     // tile E2 landed
    BARRIER();
    QUAD(a1_, b_lo, 1, 0);
    BARRIER();
  }
#undef RD_A8
#undef RD_B4
#undef QUAD
#undef BARRIER
#undef RDALL
  const int rb = bm + wm * 128 + lg * 4, cb = bn + wn * 64 + lr;
#pragma unroll
  for (int i = 0; i < 8; ++i)
#pragma unroll
    for (int j = 0; j < 4; ++j)
#pragma unroll
      for (int r = 0; r < 4; ++r) {
        size_t idx = (size_t)(rb + i * 16 + r) * N + (cb + j * 16);
        if (BF16OUT) ((short*)Cv)[idx] = f2bf(acc[i][j][r]);
        else         ((float*)Cv)[idx] = acc[i][j][r];
      }
}

// ---------- Flash attention, m214 structure; qb<->z balance flip ----------
__global__ __launch_bounds__(512, 2) void fattn2(const short* __restrict__ qkv,
                                                 const short* __restrict__ vt,
                                                 short* __restrict__ ao) {
  const int b = blockIdx.z, h = blockIdx.y;
  const int qb = b ? (int)gridDim.x - 1 - blockIdx.x : blockIdx.x;
  const int kvh = h >> 2;
  const int tid = threadIdx.x;
  const int lane = tid & 63, wid = tid >> 6;
  const int l31 = lane & 31, hi = lane >> 5;
  __shared__ __align__(16) short Ks[2][64 * 128];
  __shared__ __align__(16) short Vs[2][128 * 64];

  const int q0w   = qb * 256 + wid * 32;
  const int qg    = q0w + l31;
  const int tmaxw = q0w >> 6;
  const int NT    = 4 * qb + 4;

  bfrag qf[8];
  {
    const short* qp = qkv + (size_t)(b * 2048 + qg) * 6144 + h * 128 + hi * 8;
#pragma unroll
    for (int kk = 0; kk < 8; ++kk) qf[kk] = *(const bfrag*)(qp + kk * 16);
  }

  const int kr0 = tid >> 4, kcc = tid & 15;
  const int vd0 = tid >> 3, vkc = tid & 7;
  const int kro[2] = { kr0, kr0 + 32 };
  const int vdo[2] = { vd0, vd0 + 64 };
  int kldst[2], vldst[2];
#pragma unroll
  for (int i = 0; i < 2; ++i) {
    kldst[i] = (kro[i] * 256 + kcc * 16) ^ ((kro[i] & 7) << 4);
    vldst[i] = (vdo[i] * 128 + vkc * 16) ^ ((vdo[i] & 7) << 4);
  }
  const short* base_k = qkv + (size_t)(b * 2048) * 6144 + 4096 + kvh * 128;
  const short* base_v = vt + (size_t)((b * 8 + kvh) * 128) * 2048;

  {
    s16x8 kr_[2], vr_[2];
#pragma unroll
    for (int i = 0; i < 2; ++i) {
      kr_[i] = *(const s16x8*)(base_k + (size_t)kro[i] * 6144 + kcc * 8);
      vr_[i] = *(const s16x8*)(base_v + (size_t)vdo[i] * 2048 + vkc * 8);
    }
#pragma unroll
    for (int i = 0; i < 2; ++i) {
      *(s16x8*)((char*)Ks[0] + kldst[i]) = kr_[i];
      *(s16x8*)((char*)Vs[0] + vldst[i]) = vr_[i];
    }
  }
  __syncthreads();

  f32x16 o[4] = {};
  float m = -3.0e38f, l = 0.f;
  const float c0 = 0.08838834764831845f * 1.4426950408889634f;
  const int  sw = (l31 & 7) << 4;

  for (int t = 0; t < NT; ++t) {
    const int cur = t & 1;
    s16x8 kr_[2], vr_[2];
    const bool pf = (t + 1 < NT);
    if (pf) {
#pragma unroll
      for (int i = 0; i < 2; ++i) {
        kr_[i] = *(const s16x8*)(base_k + (size_t)((t + 1) * 64 + kro[i]) * 6144 + kcc * 8);
        vr_[i] = *(const s16x8*)(base_v + (size_t)vdo[i] * 2048 + (t + 1) * 64 + vkc * 8);
      }
    }
    if (t <= tmaxw) {
      f32x16 st[2] = {};
      {
        const char* kb = (const char*)Ks[cur] + l31 * 256;
        __builtin_amdgcn_s_setprio(1);
#pragma unroll
        for (int kk = 0; kk < 8; ++kk) {
          const int ko = (kk * 32 + hi * 16) ^ sw;
          bfrag kf0 = *(const bfrag*)(kb + ko);
          bfrag kf1 = *(const bfrag*)(kb + 8192 + ko);
          st[0] = __builtin_amdgcn_mfma_f32_32x32x16_bf16(kf0, qf[kk], st[0], 0, 0, 0);
          st[1] = __builtin_amdgcn_mfma_f32_32x32x16_bf16(kf1, qf[kk], st[1], 0, 0, 0);
        }
        __builtin_amdgcn_s_setprio(0);
      }
      if (t == tmaxw) {
        const int kb0 = t * 64 + 4 * hi;
#pragma unroll
        for (int kt = 0; kt < 2; ++kt)
#pragma unroll
          for (int r = 0; r < 16; ++r) {
            int k = kb0 + kt * 32 + (r & 3) + 8 * (r >> 2);
            if (k > qg) st[kt][r] = -3.0e38f;
          }
      }
      float mt = -3.0e38f;
#pragma unroll
      for (int kt = 0; kt < 2; ++kt)
#pragma unroll
        for (int r = 0; r < 16; ++r) mt = fmaxf(mt, st[kt][r]);
      mt = fmaxf(mt, __shfl_xor(mt, 32, 64));
      if (!__all((mt - m) * c0 <= 8.0f)) {
        float nm = fmaxf(m, mt);
        float fe = exp2f((m - nm) * c0);
        m = nm;
        l *= fe;
#pragma unroll
        for (int dt = 0; dt < 4; ++dt)
#pragma unroll
          for (int r = 0; r < 16; ++r) o[dt][r] *= fe;
      }
      const float mc = m * c0;
      float ps = 0.f;
#pragma unroll
      for (int kt = 0; kt < 2; ++kt)
#pragma unroll
        for (int r = 0; r < 16; ++r) {
          float p = exp2f(st[kt][r] * c0 - mc);
          st[kt][r] = p;
          ps += p;
        }
      ps += __shfl_xor(ps, 32, 64);
      l += ps;
      bfrag pfr[4];
#pragma unroll
      for (int kt = 0; kt < 2; ++kt) {
        u32x2 a0 = __builtin_amdgcn_permlane32_swap(cvtpk(st[kt][0],  st[kt][1]),
                                                    cvtpk(st[kt][4],  st[kt][5]),  0, 0);
        u32x2 a1 = __builtin_amdgcn_permlane32_swap(cvtpk(st[kt][2],  st[kt][3]),
                                                    cvtpk(st[kt][6],  st[kt][7]),  0, 0);
        u32x2 b0 = __builtin_amdgcn_permlane32_swap(cvtpk(st[kt][8],  st[kt][9]),
                                                    cvtpk(st[kt][12], st[kt][13]), 0, 0);
        u32x2 b1 = __builtin_amdgcn_permlane32_swap(cvtpk(st[kt][10], st[kt][11]),
                                                    cvtpk(st[kt][14], st[kt][15]), 0, 0);
        u32x4 w0 = { a0.x, a1.x, a0.y, a1.y };
        u32x4 w1 = { b0.x, b1.x, b0.y, b1.y };
        pfr[kt * 2]     = __builtin_bit_cast(bfrag, w0);
        pfr[kt * 2 + 1] = __builtin_bit_cast(bfrag, w1);
      }
      __builtin_amdgcn_s_setprio(1);
#pragma unroll
      for (int ks = 0; ks < 4; ++ks) {
        const char* vb = (const char*)Vs[cur] + l31 * 128 + ((ks * 32 + hi * 16) ^ sw);
#pragma unroll
        for (int dt = 0; dt < 4; ++dt) {
          bfrag vf = *(const bfrag*)(vb + dt * 4096);
          o[dt] = __builtin_amdgcn_mfma_f32_32x32x16_bf16(vf, pfr[ks], o[dt], 0, 0, 0);
        }
      }
      __builtin_amdgcn_s_setprio(0);
    }
    __syncthreads();
    if (pf) {
#pragma unroll
      for (int i = 0; i < 2; ++i) {
        *(s16x8*)((char*)Ks[cur ^ 1] + kldst[i]) = kr_[i];
        *(s16x8*)((char*)Vs[cur ^ 1] + vldst[i]) = vr_[i];
      }
    }
    __syncthreads();
  }
  const float linv = 1.f / l;
  short* aop = ao + (size_t)(b * 2048 + qg) * 4096 + h * 128 + 4 * hi;
#pragma unroll
  for (int dt = 0; dt < 4; ++dt)
#pragma unroll
    for (int r = 0; r < 16; ++r) {
      int d = dt * 32 + (r & 3) + 8 * (r >> 2);
      aop[d] = f2bf(o[dt][r] * linv);
    }
}

// ---------- launch ----------
extern "C" void kernel_launch(void* const* d_in, const int* in_sizes, int n_in,
                              void* d_out, int out_size, void* d_ws, size_t ws_size,
                              hipStream_t stream) {
  const float* x  = (const float*)d_in[0];
  const float* wq = (const float*)d_in[1];
  const float* wk = (const float*)d_in[2];
  const float* wv = (const float*)d_in[3];
  const float* wo = (const float*)d_in[4];
  const float* fc = (const float*)d_in[7];
  const float* fs = (const float*)d_in[8];

  char* ws = (char*)d_ws;
  short* xb    = (short*)(ws);                    // [4096][4096] bf16; reused as ao
  short* ao    = xb;
  short* wqkvb = (short*)(ws + 33554432ull);      // [6144][4096] bf16
  short* qkv   = (short*)(ws + 83886080ull);      // [4096][6144] bf16 (V region unused)
  short* vt    = (short*)(ws + 134217728ull);     // [2][8][128][2048] bf16
  short* wob   = (short*)(ws + 167772160ull);     // [4096][4096] bf16

  cvt4<<<40960, 256, 0, stream>>>(x, wq, wk, wv,
                                  xb, wqkvb, wqkvb + 16777216, wqkvb + 20971520);
  gemm128n<true><<<768, 512, 0, stream>>>(xb, wqkvb, qkv, vt,
                                          4096, 6144, 4096, 24, fc, fs);
  cvt_f32_bf16<<<16384, 256, 0, stream>>>(wo, wob, 4194304);
  fattn2<<<dim3(8, 32, 2), 512, 0, stream>>>(qkv, vt, ao);
  gemm256p<false><<<256, 512, 0, stream>>>(ao, wob, (float*)d_out, 4096, 4096, 4096, 16);
}

// Round 17
// 476.554 us; speedup vs baseline: 1.1883x; 1.1883x over previous
//
#include <hip/hip_runtime.h>
#include <hip/hip_bf16.h>
#include <math.h>

// ---------- types ----------
typedef __attribute__((ext_vector_type(8)))  __bf16 bfrag;   // MFMA A/B operand (8 bf16)
typedef __attribute__((ext_vector_type(4)))  float  f32x4;
typedef __attribute__((ext_vector_type(16))) float  f32x16;  // 32x32 MFMA C/D
typedef __attribute__((ext_vector_type(8)))  short  s16x8;
typedef __attribute__((ext_vector_type(4)))  short  s16x4;
typedef __attribute__((ext_vector_type(2)))  unsigned u32x2;
typedef __attribute__((ext_vector_type(4)))  unsigned u32x4;

__device__ __forceinline__ short f2bf(float f) {
  return (short)__builtin_bit_cast(unsigned short, (__bf16)f);
}
__device__ __forceinline__ float bf2f(short s) {
  return (float)__builtin_bit_cast(__bf16, (unsigned short)s);
}
__device__ __forceinline__ unsigned cvtpk(float lo, float hi_) {
  unsigned r;
  asm("v_cvt_pk_bf16_f32 %0, %1, %2" : "=v"(r) : "v"(lo), "v"(hi_));
  return r;
}
__device__ __forceinline__ void gll16(const void* g, void* l) {
  __builtin_amdgcn_global_load_lds((const __attribute__((address_space(1))) void*)g,
                                   (__attribute__((address_space(3))) void*)l, 16, 0, 0);
}

// ---------- f32 -> bf16 converts (nontemporal input reads: read-once data) ----------
__global__ __launch_bounds__(256) void cvt_f32_bf16(const float* __restrict__ in,
                                                    short* __restrict__ out, int n4) {
  int i = blockIdx.x * 256 + threadIdx.x;
  if (i >= n4) return;
  f32x4 v = __builtin_nontemporal_load((const f32x4*)in + i);
  s16x4 o;
  o.x = f2bf(v.x); o.y = f2bf(v.y); o.z = f2bf(v.z); o.w = f2bf(v.w);
  ((s16x4*)out)[i] = o;
}

__global__ __launch_bounds__(256) void cvt4(const float* __restrict__ x,
                                            const float* __restrict__ wq,
                                            const float* __restrict__ wk,
                                            const float* __restrict__ wv,
                                            short* __restrict__ xb,
                                            short* __restrict__ wqb,
                                            short* __restrict__ wkb,
                                            short* __restrict__ wvb) {
  const int b = blockIdx.x;
  const float* in; short* out; int base;
  if (b < 16384)      { in = x;  out = xb;  base = 0; }
  else if (b < 32768) { in = wq; out = wqb; base = 16384 * 256; }
  else if (b < 36864) { in = wk; out = wkb; base = 32768 * 256; }
  else                { in = wv; out = wvb; base = 36864 * 256; }
  const int idx = b * 256 + threadIdx.x - base;
  f32x4 v = __builtin_nontemporal_load((const f32x4*)in + idx);
  s16x4 o;
  o.x = f2bf(v.x); o.y = f2bf(v.y); o.z = f2bf(v.z); o.w = f2bf(v.w);
  ((s16x4*)out)[idx] = o;
}

// ---------- shared staging macro (half-tile = 128 rows x 64 cols, 2 gll16/thr) ----------
#define STG_(OP, OPs, boff, bb, hh, kt_, Kd)                                     \
  do {                                                                           \
    _Pragma("unroll")                                                            \
    for (int s = 0; s < 2; ++s)                                                  \
      gll16(OP + (size_t)(boff + (hh) * 128 + s * 64 + r0) * Kd + (kt_) * 64 + csrc * 8, \
            (char*)OPs[bb] + ((hh) * 128 + s * 64 + wid * 8) * 128);             \
  } while (0)

// ---------- GEMM 128x256 (QKV; 768 blocks) + fused RoPE + fused V-transpose ----------
// Q/K blocks (bn<5120): RoPE in epilogue (pairs in lanes lr, lr^1).
// V blocks (bn>=5120): write acc DIRECTLY TRANSPOSED to vt[b][kvh][d][s]
// (4 consecutive tokens per s16x4 store); qkv V-region never written.
template<bool ROPE>
__global__ __launch_bounds__(512) void gemm128n(const short* __restrict__ A,
                                                const short* __restrict__ B,
                                                short* __restrict__ C,
                                                short* __restrict__ vt,
                                                int M, int N, int K, int NBX,
                                                const float* __restrict__ fcos,
                                                const float* __restrict__ fsin) {
  __shared__ __align__(16) short As[2][128 * 64];
  __shared__ __align__(16) short Bs[2][256 * 64];
  const int tid = threadIdx.x, lane = tid & 63, wid = tid >> 6;
  const int lr = lane & 15, lg = lane >> 4;
  const int wm = wid >> 2, wn = wid & 3;
  const int orig = blockIdx.x;
  const int xc = orig & 7, o8 = orig >> 3;
  const int s8 = o8 >> 5, t8 = o8 & 31;
  const int bmi = ((xc >> 1) << 3) + (t8 >> 2);
  const int bni = (xc & 1) * (NBX >> 1) + (s8 << 2) + (t8 & 3);
  const int bm = bmi << 7, bn = bni << 8;
  const int NT = K >> 6;
  const int r0 = tid >> 3;
  const int c0 = tid & 7;
  const int csrc = c0 ^ (r0 & 7);

  int ch[2];
#pragma unroll
  for (int ks = 0; ks < 2; ++ks) ch[ks] = (((ks << 2) | lg) ^ (lr & 7)) << 4;
  const int aoff  = (wm * 64 + lr) * 128;
  const int boff2 = (wn * 32 + lr) * 128;

#define RD_A(dst, bb)                                                            \
  do {                                                                           \
    const char* ab = (const char*)As[bb] + aoff;                                 \
    _Pragma("unroll") for (int i = 0; i < 4; ++i)                                \
      _Pragma("unroll") for (int ks = 0; ks < 2; ++ks)                           \
        dst[i][ks] = *(const bfrag*)(ab + i * 2048 + ch[ks]);                    \
  } while (0)
#define RD_B(dst, bb, jh)                                                        \
  do {                                                                           \
    const char* bp = (const char*)Bs[bb] + boff2 + (jh) * 16384;                 \
    _Pragma("unroll") for (int j = 0; j < 2; ++j)                                \
      _Pragma("unroll") for (int ks = 0; ks < 2; ++ks)                           \
        dst[j][ks] = *(const bfrag*)(bp + j * 2048 + ch[ks]);                    \
  } while (0)
#define MFMA16(af, bf, jh)                                                       \
  do {                                                                           \
    __builtin_amdgcn_s_setprio(1);                                               \
    _Pragma("unroll") for (int ks = 0; ks < 2; ++ks)                             \
      _Pragma("unroll") for (int i = 0; i < 4; ++i)                              \
        _Pragma("unroll") for (int j = 0; j < 2; ++j)                            \
          acc[i][(jh) * 2 + j] = __builtin_amdgcn_mfma_f32_16x16x32_bf16(        \
              af[i][ks], bf[j][ks], acc[i][(jh) * 2 + j], 0, 0, 0);              \
    __builtin_amdgcn_s_setprio(0);                                               \
  } while (0)

  STG_(A, As, bm, 0, 0, 0, K);
  STG_(B, Bs, bn, 0, 0, 0, K);
  STG_(B, Bs, bn, 0, 1, 0, K);
  if (NT > 1) {
    STG_(A, As, bm, 1, 0, 1, K);
    STG_(B, Bs, bn, 1, 0, 1, K);
    asm volatile("s_waitcnt vmcnt(4)" ::: "memory");
  } else {
    asm volatile("s_waitcnt vmcnt(0)" ::: "memory");
  }
  __builtin_amdgcn_s_barrier();
  __builtin_amdgcn_sched_barrier(0);

  f32x4 acc[4][4] = {};
  bfrag a_[4][2], b_lo[2][2], b_hi[2][2];

  for (int kt = 0; kt < NT; ++kt) {
    const int b = kt & 1;
    RD_A(a_, b);
    RD_B(b_lo, b, 0);
    if (kt + 1 < NT) STG_(B, Bs, bn, b ^ 1, 1, kt + 1, K);
    MFMA16(a_, b_lo, 0);
    __builtin_amdgcn_s_barrier();
    __builtin_amdgcn_sched_barrier(0);
    RD_B(b_hi, b, 1);
    if (kt + 2 < NT) {
      STG_(A, As, bm, b, 0, kt + 2, K);
      STG_(B, Bs, bn, b, 0, kt + 2, K);
    }
    MFMA16(a_, b_hi, 1);
    if (kt + 1 < NT) {
      if (kt + 2 < NT) asm volatile("s_waitcnt vmcnt(4)" ::: "memory");
      else             asm volatile("s_waitcnt vmcnt(0)" ::: "memory");
      __builtin_amdgcn_s_barrier();
      __builtin_amdgcn_sched_barrier(0);
    }
  }
#undef RD_A
#undef RD_B
#undef MFMA16
  // ---- epilogue: RoPE (Q/K) | transposed-V | plain ----
  const int rb = bm + wm * 64 + lg * 4, cb = bn + wn * 32 + lr;
  if (ROPE && bn < 5120) {
    const bool odd = (lr & 1) != 0;
#pragma unroll
    for (int j = 0; j < 2; ++j) {
      const int iidx = (wn * 32 + j * 16 + lr) >> 1;
#pragma unroll
      for (int i = 0; i < 4; ++i)
#pragma unroll
        for (int r = 0; r < 4; ++r) {
          const int row = rb + i * 16 + r;
          const int sp = row & 2047;
          const float c  = fcos[sp * 64 + iidx];
          const float sn = fsin[sp * 64 + iidx];
#pragma unroll
          for (int jh = 0; jh < 2; ++jh) {
            float own = acc[i][jh * 2 + j][r];
            float par = __shfl_xor(own, 1, 64);
            float out = odd ? (par * sn + own * c) : (own * c - par * sn);
            C[(size_t)row * N + (cb + jh * 128 + j * 16)] = f2bf(out);
          }
        }
    }
  } else if (ROPE) {
#pragma unroll
    for (int jh = 0; jh < 2; ++jh)
#pragma unroll
      for (int j = 0; j < 2; ++j) {
        const int vcol = cb + jh * 128 + j * 16 - 5120;   // 0..1023
        const int kvh = vcol >> 7, d = vcol & 127;
#pragma unroll
        for (int i = 0; i < 4; ++i) {
          const int row0 = rb + i * 16;                   // 4 consecutive tokens
          const int bb = row0 >> 11, s0 = row0 & 2047;
          s16x4 v;
#pragma unroll
          for (int r = 0; r < 4; ++r) v[r] = f2bf(acc[i][jh * 2 + j][r]);
          *(s16x4*)(vt + (size_t)((bb * 8 + kvh) * 128 + d) * 2048 + s0) = v;
        }
      }
  } else {
#pragma unroll
    for (int i = 0; i < 4; ++i)
#pragma unroll
      for (int jh = 0; jh < 2; ++jh)
#pragma unroll
        for (int j = 0; j < 2; ++j)
#pragma unroll
          for (int r = 0; r < 4; ++r)
            C[(size_t)(rb + i * 16 + r) * N + (cb + jh * 128 + j * 16)] =
                f2bf(acc[i][jh * 2 + j][r]);
  }
}

// ---------- GEMM 256x256, BK=64, m201 8-phase (out-proj; 256 blocks) ----------
template<bool BF16OUT>
__global__ __launch_bounds__(512) void gemm256p(const short* __restrict__ A,
                                                const short* __restrict__ B,
                                                void* __restrict__ Cv,
                                                int M, int N, int K, int NBX) {
  __shared__ __align__(16) short As[2][256 * 64];   // 64 KB
  __shared__ __align__(16) short Bs[2][256 * 64];   // 64 KB
  const int tid = threadIdx.x, lane = tid & 63, wid = tid >> 6;
  const int lr = lane & 15, lg = lane >> 4;
  const int wm = wid >> 2, wn = wid & 3;
  const int orig = blockIdx.x;
  const int xc = orig & 7, o8 = orig >> 3;
  const int bmi = ((xc >> 1) << 2) + (o8 & 3);
  const int bni = (xc & 1) * (NBX >> 1) + (o8 >> 2);
  const int bm = bmi << 8, bn = bni << 8;
  const int NT = K >> 6;
  const int r0 = tid >> 3;
  const int c0 = tid & 7;
  const int csrc = c0 ^ (r0 & 7);

  int ch[2];
#pragma unroll
  for (int ks = 0; ks < 2; ++ks) ch[ks] = (((ks << 2) | lg) ^ (lr & 7)) << 4;
  const int aoff = (wm * 128 + lr) * 128;
  const int boff = (wn * 64 + lr) * 128;

#define RD_A8(dst, bb, ih)                                                       \
  do {                                                                           \
    const char* ab = (const char*)As[bb] + aoff + (ih) * 8192;                   \
    _Pragma("unroll") for (int i = 0; i < 4; ++i)                                \
      _Pragma("unroll") for (int ks = 0; ks < 2; ++ks)                           \
        dst[i][ks] = *(const bfrag*)(ab + i * 2048 + ch[ks]);                    \
  } while (0)
#define RD_B4(dst, bb, jh)                                                       \
  do {                                                                           \
    const char* bp = (const char*)Bs[bb] + boff + (jh) * 4096;                   \
    _Pragma("unroll") for (int j = 0; j < 2; ++j)                                \
      _Pragma("unroll") for (int ks = 0; ks < 2; ++ks)                           \
        dst[j][ks] = *(const bfrag*)(bp + j * 2048 + ch[ks]);                    \
  } while (0)
#define QUAD(af, bf, ih, jh)                                                     \
  do {                                                                           \
    __builtin_amdgcn_s_setprio(1);                                               \
    _Pragma("unroll") for (int ks = 0; ks < 2; ++ks)                             \
      _Pragma("unroll") for (int i = 0; i < 4; ++i)                              \
        _Pragma("unroll") for (int j = 0; j < 2; ++j)                            \
          acc[(ih) * 4 + i][(jh) * 2 + j] = __builtin_amdgcn_mfma_f32_16x16x32_bf16( \
              af[i][ks], bf[j][ks], acc[(ih) * 4 + i][(jh) * 2 + j], 0, 0, 0);   \
    __builtin_amdgcn_s_setprio(0);                                               \
  } while (0)
#define BARRIER() do { __builtin_amdgcn_s_barrier(); __builtin_amdgcn_sched_barrier(0); } while (0)

  STG_(A, As, bm, 0, 0, 0, K); STG_(A, As, bm, 0, 1, 0, K);
  STG_(B, Bs, bn, 0, 0, 0, K); STG_(B, Bs, bn, 0, 1, 0, K);
  STG_(B, Bs, bn, 1, 0, 1, K); STG_(B, Bs, bn, 1, 1, 1, K);
  asm volatile("s_waitcnt vmcnt(4)" ::: "memory");
  BARRIER();

  f32x4 acc[8][4] = {};
  bfrag a_[4][2], b_lo[2][2], b_hi[2][2];
  const int NI = NT >> 1;

  for (int it = 0; it < NI; ++it) {
    const int O  = 2 * it + 1;
    int E2 = 2 * it + 2; if (E2 >= NT) E2 = 0;
    int O2 = 2 * it + 3; if (O2 >= NT) O2 = 0;
    RD_A8(a_, 0, 0);
    RD_B4(b_lo, 0, 0);
    STG_(A, As, bm, 1, 0, O, K);
    BARRIER();
    asm volatile("s_waitcnt lgkmcnt(0)" ::: "memory");
    QUAD(a_, b_lo, 0, 0);
    BARRIER();
    RD_B4(b_hi, 0, 1);
    STG_(A, As, bm, 1, 1, O, K);
    BARRIER();
    asm volatile("s_waitcnt lgkmcnt(0)" ::: "memory");
    QUAD(a_, b_hi, 0, 1);
    BARRIER();
    RD_A8(a_, 0, 1);
    STG_(B, Bs, bn, 0, 0, E2, K);
    BARRIER();
    asm volatile("s_waitcnt lgkmcnt(0)" ::: "memory");
    QUAD(a_, b_hi, 1, 1);
    BARRIER();
    STG_(B, Bs, bn, 0, 1, E2, K);
    asm volatile("s_waitcnt vmcnt(4)" ::: "memory");
    BARRIER();
    QUAD(a_, b_lo, 1, 0);
    BARRIER();
    RD_A8(a_, 1, 0);
    RD_B4(b_lo, 1, 0);
    STG_(A, As, bm, 0, 0, E2, K);
    BARRIER();
    asm volatile("s_waitcnt lgkmcnt(0)" ::: "memory");
    QUAD(a_, b_lo, 0, 0);
    BARRIER();
    RD_B4(b_hi, 1, 1);
    STG_(A, As, bm, 0, 1, E2, K);
    BARRIER();
    asm volatile("s_waitcnt lgkmcnt(0)" ::: "memory");
    QUAD(a_, b_hi, 0, 1);
    BARRIER();
    RD_A8(a_, 1, 1);
    STG_(B, Bs, bn, 1, 0, O2, K);
    BARRIER();
    asm volatile("s_waitcnt lgkmcnt(0)" ::: "memory");
    QUAD(a_, b_hi, 1, 1);
    BARRIER();
    STG_(B, Bs, bn, 1, 1, O2, K);
    asm volatile("s_waitcnt vmcnt(4)" ::: "memory");
    BARRIER();
    QUAD(a_, b_lo, 1, 0);
    BARRIER();
  }
#undef RD_A8
#undef RD_B4
#undef QUAD
#undef BARRIER
  const int rb = bm + wm * 128 + lg * 4, cb = bn + wn * 64 + lr;
#pragma unroll
  for (int i = 0; i < 8; ++i)
#pragma unroll
    for (int j = 0; j < 4; ++j)
#pragma unroll
      for (int r = 0; r < 4; ++r) {
        size_t idx = (size_t)(rb + i * 16 + r) * N + (cb + j * 16);
        if (BF16OUT) ((short*)Cv)[idx] = f2bf(acc[i][j][r]);
        else         ((float*)Cv)[idx] = acc[i][j][r];
      }
}

// ---------- Flash attention, m214 structure; qb<->z balance flip ----------
__global__ __launch_bounds__(512, 2) void fattn2(const short* __restrict__ qkv,
                                                 const short* __restrict__ vt,
                                                 short* __restrict__ ao) {
  const int b = blockIdx.z, h = blockIdx.y;
  const int qb = b ? (int)gridDim.x - 1 - blockIdx.x : blockIdx.x;
  const int kvh = h >> 2;
  const int tid = threadIdx.x;
  const int lane = tid & 63, wid = tid >> 6;
  const int l31 = lane & 31, hi = lane >> 5;
  __shared__ __align__(16) short Ks[2][64 * 128];
  __shared__ __align__(16) short Vs[2][128 * 64];

  const int q0w   = qb * 256 + wid * 32;
  const int qg    = q0w + l31;
  const int tmaxw = q0w >> 6;
  const int NT    = 4 * qb + 4;

  bfrag qf[8];
  {
    const short* qp = qkv + (size_t)(b * 2048 + qg) * 6144 + h * 128 + hi * 8;
#pragma unroll
    for (int kk = 0; kk < 8; ++kk) qf[kk] = *(const bfrag*)(qp + kk * 16);
  }

  const int kr0 = tid >> 4, kcc = tid & 15;
  const int vd0 = tid >> 3, vkc = tid & 7;
  const int kro[2] = { kr0, kr0 + 32 };
  const int vdo[2] = { vd0, vd0 + 64 };
  int kldst[2], vldst[2];
#pragma unroll
  for (int i = 0; i < 2; ++i) {
    kldst[i] = (kro[i] * 256 + kcc * 16) ^ ((kro[i] & 7) << 4);
    vldst[i] = (vdo[i] * 128 + vkc * 16) ^ ((vdo[i] & 7) << 4);
  }
  const short* base_k = qkv + (size_t)(b * 2048) * 6144 + 4096 + kvh * 128;
  const short* base_v = vt + (size_t)((b * 8 + kvh) * 128) * 2048;

  {
    s16x8 kr_[2], vr_[2];
#pragma unroll
    for (int i = 0; i < 2; ++i) {
      kr_[i] = *(const s16x8*)(base_k + (size_t)kro[i] * 6144 + kcc * 8);
      vr_[i] = *(const s16x8*)(base_v + (size_t)vdo[i] * 2048 + vkc * 8);
    }
#pragma unroll
    for (int i = 0; i < 2; ++i) {
      *(s16x8*)((char*)Ks[0] + kldst[i]) = kr_[i];
      *(s16x8*)((char*)Vs[0] + vldst[i]) = vr_[i];
    }
  }
  __syncthreads();

  f32x16 o[4] = {};
  float m = -3.0e38f, l = 0.f;
  const float c0 = 0.08838834764831845f * 1.4426950408889634f;
  const int  sw = (l31 & 7) << 4;

  for (int t = 0; t < NT; ++t) {
    const int cur = t & 1;
    s16x8 kr_[2], vr_[2];
    const bool pf = (t + 1 < NT);
    if (pf) {
#pragma unroll
      for (int i = 0; i < 2; ++i) {
        kr_[i] = *(const s16x8*)(base_k + (size_t)((t + 1) * 64 + kro[i]) * 6144 + kcc * 8);
        vr_[i] = *(const s16x8*)(base_v + (size_t)vdo[i] * 2048 + (t + 1) * 64 + vkc * 8);
      }
    }
    if (t <= tmaxw) {
      f32x16 st[2] = {};
      {
        const char* kb = (const char*)Ks[cur] + l31 * 256;
        __builtin_amdgcn_s_setprio(1);
#pragma unroll
        for (int kk = 0; kk < 8; ++kk) {
          const int ko = (kk * 32 + hi * 16) ^ sw;
          bfrag kf0 = *(const bfrag*)(kb + ko);
          bfrag kf1 = *(const bfrag*)(kb + 8192 + ko);
          st[0] = __builtin_amdgcn_mfma_f32_32x32x16_bf16(kf0, qf[kk], st[0], 0, 0, 0);
          st[1] = __builtin_amdgcn_mfma_f32_32x32x16_bf16(kf1, qf[kk], st[1], 0, 0, 0);
        }
        __builtin_amdgcn_s_setprio(0);
      }
      if (t == tmaxw) {
        const int kb0 = t * 64 + 4 * hi;
#pragma unroll
        for (int kt = 0; kt < 2; ++kt)
#pragma unroll
          for (int r = 0; r < 16; ++r) {
            int k = kb0 + kt * 32 + (r & 3) + 8 * (r >> 2);
            if (k > qg) st[kt][r] = -3.0e38f;
          }
      }
      float mt = -3.0e38f;
#pragma unroll
      for (int kt = 0; kt < 2; ++kt)
#pragma unroll
        for (int r = 0; r < 16; ++r) mt = fmaxf(mt, st[kt][r]);
      mt = fmaxf(mt, __shfl_xor(mt, 32, 64));
      if (!__all((mt - m) * c0 <= 8.0f)) {
        float nm = fmaxf(m, mt);
        float fe = exp2f((m - nm) * c0);
        m = nm;
        l *= fe;
#pragma unroll
        for (int dt = 0; dt < 4; ++dt)
#pragma unroll
          for (int r = 0; r < 16; ++r) o[dt][r] *= fe;
      }
      const float mc = m * c0;
      float ps = 0.f;
#pragma unroll
      for (int kt = 0; kt < 2; ++kt)
#pragma unroll
        for (int r = 0; r < 16; ++r) {
          float p = exp2f(st[kt][r] * c0 - mc);
          st[kt][r] = p;
          ps += p;
        }
      ps += __shfl_xor(ps, 32, 64);
      l += ps;
      bfrag pfr[4];
#pragma unroll
      for (int kt = 0; kt < 2; ++kt) {
        u32x2 a0 = __builtin_amdgcn_permlane32_swap(cvtpk(st[kt][0],  st[kt][1]),
                                                    cvtpk(st[kt][4],  st[kt][5]),  0, 0);
        u32x2 a1 = __builtin_amdgcn_permlane32_swap(cvtpk(st[kt][2],  st[kt][3]),
                                                    cvtpk(st[kt][6],  st[kt][7]),  0, 0);
        u32x2 b0 = __builtin_amdgcn_permlane32_swap(cvtpk(st[kt][8],  st[kt][9]),
                                                    cvtpk(st[kt][12], st[kt][13]), 0, 0);
        u32x2 b1 = __builtin_amdgcn_permlane32_swap(cvtpk(st[kt][10], st[kt][11]),
                                                    cvtpk(st[kt][14], st[kt][15]), 0, 0);
        u32x4 w0 = { a0.x, a1.x, a0.y, a1.y };
        u32x4 w1 = { b0.x, b1.x, b0.y, b1.y };
        pfr[kt * 2]     = __builtin_bit_cast(bfrag, w0);
        pfr[kt * 2 + 1] = __builtin_bit_cast(bfrag, w1);
      }
      __builtin_amdgcn_s_setprio(1);
#pragma unroll
      for (int ks = 0; ks < 4; ++ks) {
        const char* vb = (const char*)Vs[cur] + l31 * 128 + ((ks * 32 + hi * 16) ^ sw);
#pragma unroll
        for (int dt = 0; dt < 4; ++dt) {
          bfrag vf = *(const bfrag*)(vb + dt * 4096);
          o[dt] = __builtin_amdgcn_mfma_f32_32x32x16_bf16(vf, pfr[ks], o[dt], 0, 0, 0);
        }
      }
      __builtin_amdgcn_s_setprio(0);
    }
    __syncthreads();
    if (pf) {
#pragma unroll
      for (int i = 0; i < 2; ++i) {
        *(s16x8*)((char*)Ks[cur ^ 1] + kldst[i]) = kr_[i];
        *(s16x8*)((char*)Vs[cur ^ 1] + vldst[i]) = vr_[i];
      }
    }
    __syncthreads();
  }
  const float linv = 1.f / l;
  short* aop = ao + (size_t)(b * 2048 + qg) * 4096 + h * 128 + 4 * hi;
#pragma unroll
  for (int dt = 0; dt < 4; ++dt)
#pragma unroll
    for (int r = 0; r < 16; ++r) {
      int d = dt * 32 + (r & 3) + 8 * (r >> 2);
      aop[d] = f2bf(o[dt][r] * linv);
    }
}

// ---------- launch ----------
extern "C" void kernel_launch(void* const* d_in, const int* in_sizes, int n_in,
                              void* d_out, int out_size, void* d_ws, size_t ws_size,
                              hipStream_t stream) {
  const float* x  = (const float*)d_in[0];
  const float* wq = (const float*)d_in[1];
  const float* wk = (const float*)d_in[2];
  const float* wv = (const float*)d_in[3];
  const float* wo = (const float*)d_in[4];
  const float* fc = (const float*)d_in[7];
  const float* fs = (const float*)d_in[8];

  char* ws = (char*)d_ws;
  short* xb    = (short*)(ws);                    // [4096][4096] bf16; reused as ao
  short* ao    = xb;
  short* wqkvb = (short*)(ws + 33554432ull);      // [6144][4096] bf16
  short* qkv   = (short*)(ws + 83886080ull);      // [4096][6144] bf16 (V region unused)
  short* vt    = (short*)(ws + 134217728ull);     // [2][8][128][2048] bf16
  short* wob   = (short*)(ws + 167772160ull);     // [4096][4096] bf16

  cvt4<<<40960, 256, 0, stream>>>(x, wq, wk, wv,
                                  xb, wqkvb, wqkvb + 16777216, wqkvb + 20971520);
  gemm128n<true><<<768, 512, 0, stream>>>(xb, wqkvb, qkv, vt,
                                          4096, 6144, 4096, 24, fc, fs);
  cvt_f32_bf16<<<16384, 256, 0, stream>>>(wo, wob, 4194304);
  fattn2<<<dim3(8, 32, 2), 512, 0, stream>>>(qkv, vt, ao);
  gemm256p<false><<<256, 512, 0, stream>>>(ao, wob, (float*)d_out, 4096, 4096, 4096, 16);
}

// Round 18
// 471.211 us; speedup vs baseline: 1.2018x; 1.0113x over previous
//
#include <hip/hip_runtime.h>
#include <hip/hip_bf16.h>
#include <math.h>

// ---------- types ----------
typedef __attribute__((ext_vector_type(8)))  __bf16 bfrag;   // MFMA A/B operand (8 bf16)
typedef __attribute__((ext_vector_type(4)))  float  f32x4;
typedef __attribute__((ext_vector_type(16))) float  f32x16;  // 32x32 MFMA C/D
typedef __attribute__((ext_vector_type(8)))  short  s16x8;
typedef __attribute__((ext_vector_type(4)))  short  s16x4;
typedef __attribute__((ext_vector_type(2)))  unsigned u32x2;
typedef __attribute__((ext_vector_type(4)))  unsigned u32x4;

__device__ __forceinline__ short f2bf(float f) {
  return (short)__builtin_bit_cast(unsigned short, (__bf16)f);
}
__device__ __forceinline__ float bf2f(short s) {
  return (float)__builtin_bit_cast(__bf16, (unsigned short)s);
}
__device__ __forceinline__ unsigned cvtpk(float lo, float hi_) {
  unsigned r;
  asm("v_cvt_pk_bf16_f32 %0, %1, %2" : "=v"(r) : "v"(lo), "v"(hi_));
  return r;
}
__device__ __forceinline__ void gll16(const void* g, void* l) {
  __builtin_amdgcn_global_load_lds((const __attribute__((address_space(1))) void*)g,
                                   (__attribute__((address_space(3))) void*)l, 16, 0, 0);
}

// ---------- f32 -> bf16 converts (nontemporal input reads: read-once data) ----------
__global__ __launch_bounds__(256) void cvt_f32_bf16(const float* __restrict__ in,
                                                    short* __restrict__ out, int n4) {
  int i = blockIdx.x * 256 + threadIdx.x;
  if (i >= n4) return;
  f32x4 v = __builtin_nontemporal_load((const f32x4*)in + i);
  s16x4 o;
  o.x = f2bf(v.x); o.y = f2bf(v.y); o.z = f2bf(v.z); o.w = f2bf(v.w);
  ((s16x4*)out)[i] = o;
}

__global__ __launch_bounds__(256) void cvt4(const float* __restrict__ x,
                                            const float* __restrict__ wq,
                                            const float* __restrict__ wk,
                                            const float* __restrict__ wv,
                                            short* __restrict__ xb,
                                            short* __restrict__ wqb,
                                            short* __restrict__ wkb,
                                            short* __restrict__ wvb) {
  const int b = blockIdx.x;
  const float* in; short* out; int base;
  if (b < 16384)      { in = x;  out = xb;  base = 0; }
  else if (b < 32768) { in = wq; out = wqb; base = 16384 * 256; }
  else if (b < 36864) { in = wk; out = wkb; base = 32768 * 256; }
  else                { in = wv; out = wvb; base = 36864 * 256; }
  const int idx = b * 256 + threadIdx.x - base;
  f32x4 v = __builtin_nontemporal_load((const f32x4*)in + idx);
  s16x4 o;
  o.x = f2bf(v.x); o.y = f2bf(v.y); o.z = f2bf(v.z); o.w = f2bf(v.w);
  ((s16x4*)out)[idx] = o;
}

// ---------- shared staging macro (half-tile = 128 rows x 64 cols, 2 gll16/thr) ----------
#define STG_(OP, OPs, boff, bb, hh, kt_, Kd)                                     \
  do {                                                                           \
    _Pragma("unroll")                                                            \
    for (int s = 0; s < 2; ++s)                                                  \
      gll16(OP + (size_t)(boff + (hh) * 128 + s * 64 + r0) * Kd + (kt_) * 64 + csrc * 8, \
            (char*)OPs[bb] + ((hh) * 128 + s * 64 + wid * 8) * 128);             \
  } while (0)

// ---------- GEMM 128x256 (KV part; 256 blocks) + fused K-RoPE + fused V-transpose ----------
// Local cols [0, 2048): K heads [0, vstart), V [vstart, 2048). C base pre-offset
// by caller (qkv+4096), stride N=6144. Rope iff bn < vstart (block-uniform).
template<bool ROPE>
__global__ __launch_bounds__(512) void gemm128n(const short* __restrict__ A,
                                                const short* __restrict__ B,
                                                short* __restrict__ C,
                                                short* __restrict__ vt,
                                                int M, int N, int K, int NBX, int vstart,
                                                const float* __restrict__ fcos,
                                                const float* __restrict__ fsin) {
  __shared__ __align__(16) short As[2][128 * 64];
  __shared__ __align__(16) short Bs[2][256 * 64];
  const int tid = threadIdx.x, lane = tid & 63, wid = tid >> 6;
  const int lr = lane & 15, lg = lane >> 4;
  const int wm = wid >> 2, wn = wid & 3;
  const int orig = blockIdx.x;
  const int xc = orig & 7, o8 = orig >> 3;
  const int s8 = o8 >> 5, t8 = o8 & 31;
  const int bmi = ((xc >> 1) << 3) + (t8 >> 2);
  const int bni = (xc & 1) * (NBX >> 1) + (s8 << 2) + (t8 & 3);
  const int bm = bmi << 7, bn = bni << 8;
  const int NT = K >> 6;
  const int r0 = tid >> 3;
  const int c0 = tid & 7;
  const int csrc = c0 ^ (r0 & 7);

  int ch[2];
#pragma unroll
  for (int ks = 0; ks < 2; ++ks) ch[ks] = (((ks << 2) | lg) ^ (lr & 7)) << 4;
  const int aoff  = (wm * 64 + lr) * 128;
  const int boff2 = (wn * 32 + lr) * 128;

#define RD_A(dst, bb)                                                            \
  do {                                                                           \
    const char* ab = (const char*)As[bb] + aoff;                                 \
    _Pragma("unroll") for (int i = 0; i < 4; ++i)                                \
      _Pragma("unroll") for (int ks = 0; ks < 2; ++ks)                           \
        dst[i][ks] = *(const bfrag*)(ab + i * 2048 + ch[ks]);                    \
  } while (0)
#define RD_B(dst, bb, jh)                                                        \
  do {                                                                           \
    const char* bp = (const char*)Bs[bb] + boff2 + (jh) * 16384;                 \
    _Pragma("unroll") for (int j = 0; j < 2; ++j)                                \
      _Pragma("unroll") for (int ks = 0; ks < 2; ++ks)                           \
        dst[j][ks] = *(const bfrag*)(bp + j * 2048 + ch[ks]);                    \
  } while (0)
#define MFMA16(af, bf, jh)                                                       \
  do {                                                                           \
    __builtin_amdgcn_s_setprio(1);                                               \
    _Pragma("unroll") for (int ks = 0; ks < 2; ++ks)                             \
      _Pragma("unroll") for (int i = 0; i < 4; ++i)                              \
        _Pragma("unroll") for (int j = 0; j < 2; ++j)                            \
          acc[i][(jh) * 2 + j] = __builtin_amdgcn_mfma_f32_16x16x32_bf16(        \
              af[i][ks], bf[j][ks], acc[i][(jh) * 2 + j], 0, 0, 0);              \
    __builtin_amdgcn_s_setprio(0);                                               \
  } while (0)

  STG_(A, As, bm, 0, 0, 0, K);
  STG_(B, Bs, bn, 0, 0, 0, K);
  STG_(B, Bs, bn, 0, 1, 0, K);
  if (NT > 1) {
    STG_(A, As, bm, 1, 0, 1, K);
    STG_(B, Bs, bn, 1, 0, 1, K);
    asm volatile("s_waitcnt vmcnt(4)" ::: "memory");
  } else {
    asm volatile("s_waitcnt vmcnt(0)" ::: "memory");
  }
  __builtin_amdgcn_s_barrier();
  __builtin_amdgcn_sched_barrier(0);

  f32x4 acc[4][4] = {};
  bfrag a_[4][2], b_lo[2][2], b_hi[2][2];

  for (int kt = 0; kt < NT; ++kt) {
    const int b = kt & 1;
    RD_A(a_, b);
    RD_B(b_lo, b, 0);
    if (kt + 1 < NT) STG_(B, Bs, bn, b ^ 1, 1, kt + 1, K);
    MFMA16(a_, b_lo, 0);
    __builtin_amdgcn_s_barrier();
    __builtin_amdgcn_sched_barrier(0);
    RD_B(b_hi, b, 1);
    if (kt + 2 < NT) {
      STG_(A, As, bm, b, 0, kt + 2, K);
      STG_(B, Bs, bn, b, 0, kt + 2, K);
    }
    MFMA16(a_, b_hi, 1);
    if (kt + 1 < NT) {
      if (kt + 2 < NT) asm volatile("s_waitcnt vmcnt(4)" ::: "memory");
      else             asm volatile("s_waitcnt vmcnt(0)" ::: "memory");
      __builtin_amdgcn_s_barrier();
      __builtin_amdgcn_sched_barrier(0);
    }
  }
#undef RD_A
#undef RD_B
#undef MFMA16
  // ---- epilogue: K-RoPE | transposed-V | plain ----
  const int rb = bm + wm * 64 + lg * 4, cb = bn + wn * 32 + lr;
  if (ROPE && bn < vstart) {
    const bool odd = (lr & 1) != 0;
#pragma unroll
    for (int j = 0; j < 2; ++j) {
      const int iidx = (wn * 32 + j * 16 + lr) >> 1;
#pragma unroll
      for (int i = 0; i < 4; ++i)
#pragma unroll
        for (int r = 0; r < 4; ++r) {
          const int row = rb + i * 16 + r;
          const int sp = row & 2047;
          const float c  = fcos[sp * 64 + iidx];
          const float sn = fsin[sp * 64 + iidx];
#pragma unroll
          for (int jh = 0; jh < 2; ++jh) {
            float own = acc[i][jh * 2 + j][r];
            float par = __shfl_xor(own, 1, 64);
            float out = odd ? (par * sn + own * c) : (own * c - par * sn);
            C[(size_t)row * N + (cb + jh * 128 + j * 16)] = f2bf(out);
          }
        }
    }
  } else if (ROPE) {
#pragma unroll
    for (int jh = 0; jh < 2; ++jh)
#pragma unroll
      for (int j = 0; j < 2; ++j) {
        const int vcol = cb + jh * 128 + j * 16 - vstart;  // 0..1023
        const int kvh = vcol >> 7, d = vcol & 127;
#pragma unroll
        for (int i = 0; i < 4; ++i) {
          const int row0 = rb + i * 16;                    // 4 consecutive tokens
          const int bb = row0 >> 11, s0 = row0 & 2047;
          s16x4 v;
#pragma unroll
          for (int r = 0; r < 4; ++r) v[r] = f2bf(acc[i][jh * 2 + j][r]);
          *(s16x4*)(vt + (size_t)((bb * 8 + kvh) * 128 + d) * 2048 + s0) = v;
        }
      }
  } else {
#pragma unroll
    for (int i = 0; i < 4; ++i)
#pragma unroll
      for (int jh = 0; jh < 2; ++jh)
#pragma unroll
        for (int j = 0; j < 2; ++j)
#pragma unroll
          for (int r = 0; r < 4; ++r)
            C[(size_t)(rb + i * 16 + r) * N + (cb + jh * 128 + j * 16)] =
                f2bf(acc[i][jh * 2 + j][r]);
  }
}

// ---------- GEMM 256x256, BK=64, m201 8-phase (256 blocks = 1 round) ----------
// OMODE 0: f32 plain out (out-proj). OMODE 1: bf16 out + fused Q-RoPE (cols
// are Q heads; pairs in lanes lr, lr^1; head-local col = (wn*64+j*16+lr)&127).
// N is the C row stride (6144 for Q-part, 4096 for out-proj); B indexed by K only.
template<int OMODE>
__global__ __launch_bounds__(512) void gemm256p(const short* __restrict__ A,
                                                const short* __restrict__ B,
                                                void* __restrict__ Cv,
                                                int M, int N, int K, int NBX,
                                                const float* __restrict__ fcos,
                                                const float* __restrict__ fsin) {
  __shared__ __align__(16) short As[2][256 * 64];   // 64 KB
  __shared__ __align__(16) short Bs[2][256 * 64];   // 64 KB
  const int tid = threadIdx.x, lane = tid & 63, wid = tid >> 6;
  const int lr = lane & 15, lg = lane >> 4;
  const int wm = wid >> 2, wn = wid & 3;
  const int orig = blockIdx.x;
  const int xc = orig & 7, o8 = orig >> 3;
  const int bmi = ((xc >> 1) << 2) + (o8 & 3);
  const int bni = (xc & 1) * (NBX >> 1) + (o8 >> 2);
  const int bm = bmi << 8, bn = bni << 8;
  const int NT = K >> 6;
  const int r0 = tid >> 3;
  const int c0 = tid & 7;
  const int csrc = c0 ^ (r0 & 7);

  int ch[2];
#pragma unroll
  for (int ks = 0; ks < 2; ++ks) ch[ks] = (((ks << 2) | lg) ^ (lr & 7)) << 4;
  const int aoff = (wm * 128 + lr) * 128;
  const int boff = (wn * 64 + lr) * 128;

#define RD_A8(dst, bb, ih)                                                       \
  do {                                                                           \
    const char* ab = (const char*)As[bb] + aoff + (ih) * 8192;                   \
    _Pragma("unroll") for (int i = 0; i < 4; ++i)                                \
      _Pragma("unroll") for (int ks = 0; ks < 2; ++ks)                           \
        dst[i][ks] = *(const bfrag*)(ab + i * 2048 + ch[ks]);                    \
  } while (0)
#define RD_B4(dst, bb, jh)                                                       \
  do {                                                                           \
    const char* bp = (const char*)Bs[bb] + boff + (jh) * 4096;                   \
    _Pragma("unroll") for (int j = 0; j < 2; ++j)                                \
      _Pragma("unroll") for (int ks = 0; ks < 2; ++ks)                           \
        dst[j][ks] = *(const bfrag*)(bp + j * 2048 + ch[ks]);                    \
  } while (0)
#define QUAD(af, bf, ih, jh)                                                     \
  do {                                                                           \
    __builtin_amdgcn_s_setprio(1);                                               \
    _Pragma("unroll") for (int ks = 0; ks < 2; ++ks)                             \
      _Pragma("unroll") for (int i = 0; i < 4; ++i)                              \
        _Pragma("unroll") for (int j = 0; j < 2; ++j)                            \
          acc[(ih) * 4 + i][(jh) * 2 + j] = __builtin_amdgcn_mfma_f32_16x16x32_bf16( \
              af[i][ks], bf[j][ks], acc[(ih) * 4 + i][(jh) * 2 + j], 0, 0, 0);   \
    __builtin_amdgcn_s_setprio(0);                                               \
  } while (0)
#define BARRIER() do { __builtin_amdgcn_s_barrier(); __builtin_amdgcn_sched_barrier(0); } while (0)

  STG_(A, As, bm, 0, 0, 0, K); STG_(A, As, bm, 0, 1, 0, K);
  STG_(B, Bs, bn, 0, 0, 0, K); STG_(B, Bs, bn, 0, 1, 0, K);
  STG_(B, Bs, bn, 1, 0, 1, K); STG_(B, Bs, bn, 1, 1, 1, K);
  asm volatile("s_waitcnt vmcnt(4)" ::: "memory");
  BARRIER();

  f32x4 acc[8][4] = {};
  bfrag a_[4][2], b_lo[2][2], b_hi[2][2];
  const int NI = NT >> 1;

  for (int it = 0; it < NI; ++it) {
    const int O  = 2 * it + 1;
    int E2 = 2 * it + 2; if (E2 >= NT) E2 = 0;
    int O2 = 2 * it + 3; if (O2 >= NT) O2 = 0;
    RD_A8(a_, 0, 0);
    RD_B4(b_lo, 0, 0);
    STG_(A, As, bm, 1, 0, O, K);
    BARRIER();
    asm volatile("s_waitcnt lgkmcnt(0)" ::: "memory");
    QUAD(a_, b_lo, 0, 0);
    BARRIER();
    RD_B4(b_hi, 0, 1);
    STG_(A, As, bm, 1, 1, O, K);
    BARRIER();
    asm volatile("s_waitcnt lgkmcnt(0)" ::: "memory");
    QUAD(a_, b_hi, 0, 1);
    BARRIER();
    RD_A8(a_, 0, 1);
    STG_(B, Bs, bn, 0, 0, E2, K);
    BARRIER();
    asm volatile("s_waitcnt lgkmcnt(0)" ::: "memory");
    QUAD(a_, b_hi, 1, 1);
    BARRIER();
    STG_(B, Bs, bn, 0, 1, E2, K);
    asm volatile("s_waitcnt vmcnt(4)" ::: "memory");
    BARRIER();
    QUAD(a_, b_lo, 1, 0);
    BARRIER();
    RD_A8(a_, 1, 0);
    RD_B4(b_lo, 1, 0);
    STG_(A, As, bm, 0, 0, E2, K);
    BARRIER();
    asm volatile("s_waitcnt lgkmcnt(0)" ::: "memory");
    QUAD(a_, b_lo, 0, 0);
    BARRIER();
    RD_B4(b_hi, 1, 1);
    STG_(A, As, bm, 0, 1, E2, K);
    BARRIER();
    asm volatile("s_waitcnt lgkmcnt(0)" ::: "memory");
    QUAD(a_, b_hi, 0, 1);
    BARRIER();
    RD_A8(a_, 1, 1);
    STG_(B, Bs, bn, 1, 0, O2, K);
    BARRIER();
    asm volatile("s_waitcnt lgkmcnt(0)" ::: "memory");
    QUAD(a_, b_hi, 1, 1);
    BARRIER();
    STG_(B, Bs, bn, 1, 1, O2, K);
    asm volatile("s_waitcnt vmcnt(4)" ::: "memory");
    BARRIER();
    QUAD(a_, b_lo, 1, 0);
    BARRIER();
  }
#undef RD_A8
#undef RD_B4
#undef QUAD
#undef BARRIER
  // ---- epilogue ----
  const int rb = bm + wm * 128 + lg * 4, cb = bn + wn * 64 + lr;
  if (OMODE == 1) {
    const bool odd = (lr & 1) != 0;
#pragma unroll
    for (int j = 0; j < 4; ++j) {
      const int iidx = ((wn * 64 + j * 16 + lr) & 127) >> 1;
#pragma unroll
      for (int i = 0; i < 8; ++i)
#pragma unroll
        for (int r = 0; r < 4; ++r) {
          const int row = rb + i * 16 + r;
          const int sp = row & 2047;
          const float c  = fcos[sp * 64 + iidx];
          const float sn = fsin[sp * 64 + iidx];
          float own = acc[i][j][r];
          float par = __shfl_xor(own, 1, 64);
          float out = odd ? (par * sn + own * c) : (own * c - par * sn);
          ((short*)Cv)[(size_t)row * N + (cb + j * 16)] = f2bf(out);
        }
    }
  } else {
#pragma unroll
    for (int i = 0; i < 8; ++i)
#pragma unroll
      for (int j = 0; j < 4; ++j)
#pragma unroll
        for (int r = 0; r < 4; ++r)
          ((float*)Cv)[(size_t)(rb + i * 16 + r) * N + (cb + j * 16)] = acc[i][j][r];
  }
}

// ---------- Flash attention, m214 structure; qb<->z balance flip ----------
__global__ __launch_bounds__(512, 2) void fattn2(const short* __restrict__ qkv,
                                                 const short* __restrict__ vt,
                                                 short* __restrict__ ao) {
  const int b = blockIdx.z, h = blockIdx.y;
  const int qb = b ? (int)gridDim.x - 1 - blockIdx.x : blockIdx.x;
  const int kvh = h >> 2;
  const int tid = threadIdx.x;
  const int lane = tid & 63, wid = tid >> 6;
  const int l31 = lane & 31, hi = lane >> 5;
  __shared__ __align__(16) short Ks[2][64 * 128];
  __shared__ __align__(16) short Vs[2][128 * 64];

  const int q0w   = qb * 256 + wid * 32;
  const int qg    = q0w + l31;
  const int tmaxw = q0w >> 6;
  const int NT    = 4 * qb + 4;

  bfrag qf[8];
  {
    const short* qp = qkv + (size_t)(b * 2048 + qg) * 6144 + h * 128 + hi * 8;
#pragma unroll
    for (int kk = 0; kk < 8; ++kk) qf[kk] = *(const bfrag*)(qp + kk * 16);
  }

  const int kr0 = tid >> 4, kcc = tid & 15;
  const int vd0 = tid >> 3, vkc = tid & 7;
  const int kro[2] = { kr0, kr0 + 32 };
  const int vdo[2] = { vd0, vd0 + 64 };
  int kldst[2], vldst[2];
#pragma unroll
  for (int i = 0; i < 2; ++i) {
    kldst[i] = (kro[i] * 256 + kcc * 16) ^ ((kro[i] & 7) << 4);
    vldst[i] = (vdo[i] * 128 + vkc * 16) ^ ((vdo[i] & 7) << 4);
  }
  const short* base_k = qkv + (size_t)(b * 2048) * 6144 + 4096 + kvh * 128;
  const short* base_v = vt + (size_t)((b * 8 + kvh) * 128) * 2048;

  {
    s16x8 kr_[2], vr_[2];
#pragma unroll
    for (int i = 0; i < 2; ++i) {
      kr_[i] = *(const s16x8*)(base_k + (size_t)kro[i] * 6144 + kcc * 8);
      vr_[i] = *(const s16x8*)(base_v + (size_t)vdo[i] * 2048 + vkc * 8);
    }
#pragma unroll
    for (int i = 0; i < 2; ++i) {
      *(s16x8*)((char*)Ks[0] + kldst[i]) = kr_[i];
      *(s16x8*)((char*)Vs[0] + vldst[i]) = vr_[i];
    }
  }
  __syncthreads();

  f32x16 o[4] = {};
  float m = -3.0e38f, l = 0.f;
  const float c0 = 0.08838834764831845f * 1.4426950408889634f;
  const int  sw = (l31 & 7) << 4;

  for (int t = 0; t < NT; ++t) {
    const int cur = t & 1;
    s16x8 kr_[2], vr_[2];
    const bool pf = (t + 1 < NT);
    if (pf) {
#pragma unroll
      for (int i = 0; i < 2; ++i) {
        kr_[i] = *(const s16x8*)(base_k + (size_t)((t + 1) * 64 + kro[i]) * 6144 + kcc * 8);
        vr_[i] = *(const s16x8*)(base_v + (size_t)vdo[i] * 2048 + (t + 1) * 64 + vkc * 8);
      }
    }
    if (t <= tmaxw) {
      f32x16 st[2] = {};
      {
        const char* kb = (const char*)Ks[cur] + l31 * 256;
        __builtin_amdgcn_s_setprio(1);
#pragma unroll
        for (int kk = 0; kk < 8; ++kk) {
          const int ko = (kk * 32 + hi * 16) ^ sw;
          bfrag kf0 = *(const bfrag*)(kb + ko);
          bfrag kf1 = *(const bfrag*)(kb + 8192 + ko);
          st[0] = __builtin_amdgcn_mfma_f32_32x32x16_bf16(kf0, qf[kk], st[0], 0, 0, 0);
          st[1] = __builtin_amdgcn_mfma_f32_32x32x16_bf16(kf1, qf[kk], st[1], 0, 0, 0);
        }
        __builtin_amdgcn_s_setprio(0);
      }
      if (t == tmaxw) {
        const int kb0 = t * 64 + 4 * hi;
#pragma unroll
        for (int kt = 0; kt < 2; ++kt)
#pragma unroll
          for (int r = 0; r < 16; ++r) {
            int k = kb0 + kt * 32 + (r & 3) + 8 * (r >> 2);
            if (k > qg) st[kt][r] = -3.0e38f;
          }
      }
      float mt = -3.0e38f;
#pragma unroll
      for (int kt = 0; kt < 2; ++kt)
#pragma unroll
        for (int r = 0; r < 16; ++r) mt = fmaxf(mt, st[kt][r]);
      mt = fmaxf(mt, __shfl_xor(mt, 32, 64));
      if (!__all((mt - m) * c0 <= 8.0f)) {
        float nm = fmaxf(m, mt);
        float fe = exp2f((m - nm) * c0);
        m = nm;
        l *= fe;
#pragma unroll
        for (int dt = 0; dt < 4; ++dt)
#pragma unroll
          for (int r = 0; r < 16; ++r) o[dt][r] *= fe;
      }
      const float mc = m * c0;
      float ps = 0.f;
#pragma unroll
      for (int kt = 0; kt < 2; ++kt)
#pragma unroll
        for (int r = 0; r < 16; ++r) {
          float p = exp2f(st[kt][r] * c0 - mc);
          st[kt][r] = p;
          ps += p;
        }
      ps += __shfl_xor(ps, 32, 64);
      l += ps;
      bfrag pfr[4];
#pragma unroll
      for (int kt = 0; kt < 2; ++kt) {
        u32x2 a0 = __builtin_amdgcn_permlane32_swap(cvtpk(st[kt][0],  st[kt][1]),
                                                    cvtpk(st[kt][4],  st[kt][5]),  0, 0);
        u32x2 a1 = __builtin_amdgcn_permlane32_swap(cvtpk(st[kt][2],  st[kt][3]),
                                                    cvtpk(st[kt][6],  st[kt][7]),  0, 0);
        u32x2 b0 = __builtin_amdgcn_permlane32_swap(cvtpk(st[kt][8],  st[kt][9]),
                                                    cvtpk(st[kt][12], st[kt][13]), 0, 0);
        u32x2 b1 = __builtin_amdgcn_permlane32_swap(cvtpk(st[kt][10], st[kt][11]),
                                                    cvtpk(st[kt][14], st[kt][15]), 0, 0);
        u32x4 w0 = { a0.x, a1.x, a0.y, a1.y };
        u32x4 w1 = { b0.x, b1.x, b0.y, b1.y };
        pfr[kt * 2]     = __builtin_bit_cast(bfrag, w0);
        pfr[kt * 2 + 1] = __builtin_bit_cast(bfrag, w1);
      }
      __builtin_amdgcn_s_setprio(1);
#pragma unroll
      for (int ks = 0; ks < 4; ++ks) {
        const char* vb = (const char*)Vs[cur] + l31 * 128 + ((ks * 32 + hi * 16) ^ sw);
#pragma unroll
        for (int dt = 0; dt < 4; ++dt) {
          bfrag vf = *(const bfrag*)(vb + dt * 4096);
          o[dt] = __builtin_amdgcn_mfma_f32_32x32x16_bf16(vf, pfr[ks], o[dt], 0, 0, 0);
        }
      }
      __builtin_amdgcn_s_setprio(0);
    }
    __syncthreads();
    if (pf) {
#pragma unroll
      for (int i = 0; i < 2; ++i) {
        *(s16x8*)((char*)Ks[cur ^ 1] + kldst[i]) = kr_[i];
        *(s16x8*)((char*)Vs[cur ^ 1] + vldst[i]) = vr_[i];
      }
    }
    __syncthreads();
  }
  const float linv = 1.f / l;
  short* aop = ao + (size_t)(b * 2048 + qg) * 4096 + h * 128 + 4 * hi;
#pragma unroll
  for (int dt = 0; dt < 4; ++dt)
#pragma unroll
    for (int r = 0; r < 16; ++r) {
      int d = dt * 32 + (r & 3) + 8 * (r >> 2);
      aop[d] = f2bf(o[dt][r] * linv);
    }
}

// ---------- launch ----------
extern "C" void kernel_launch(void* const* d_in, const int* in_sizes, int n_in,
                              void* d_out, int out_size, void* d_ws, size_t ws_size,
                              hipStream_t stream) {
  const float* x  = (const float*)d_in[0];
  const float* wq = (const float*)d_in[1];
  const float* wk = (const float*)d_in[2];
  const float* wv = (const float*)d_in[3];
  const float* wo = (const float*)d_in[4];
  const float* fc = (const float*)d_in[7];
  const float* fs = (const float*)d_in[8];

  char* ws = (char*)d_ws;
  short* xb    = (short*)(ws);                    // [4096][4096] bf16; reused as ao
  short* ao    = xb;
  short* wqkvb = (short*)(ws + 33554432ull);      // [6144][4096] bf16
  short* qkv   = (short*)(ws + 83886080ull);      // [4096][6144] bf16 (V region unused)
  short* vt    = (short*)(ws + 134217728ull);     // [2][8][128][2048] bf16
  short* wob   = (short*)(ws + 167772160ull);     // [4096][4096] bf16

  cvt4<<<40960, 256, 0, stream>>>(x, wq, wk, wv,
                                  xb, wqkvb, wqkvb + 16777216, wqkvb + 20971520);
  // QKV split: Q part (N=4096) on the 256^2 8-phase kernel, 1 exact round;
  // K|V part (N=2048) on the 128x256 kernel, 1 exact round.
  gemm256p<1><<<256, 512, 0, stream>>>(xb, wqkvb, qkv, 4096, 6144, 4096, 16, fc, fs);
  gemm128n<true><<<256, 512, 0, stream>>>(xb, wqkvb + 16777216ull, qkv + 4096, vt,
                                          4096, 6144, 4096, 8, 1024, fc, fs);
  cvt_f32_bf16<<<16384, 256, 0, stream>>>(wo, wob, 4194304);
  fattn2<<<dim3(8, 32, 2), 512, 0, stream>>>(qkv, vt, ao);
  gemm256p<0><<<256, 512, 0, stream>>>(ao, wob, (float*)d_out, 4096, 4096, 4096, 16,
                                       nullptr, nullptr);
}

// Round 19
// 469.557 us; speedup vs baseline: 1.2061x; 1.0035x over previous
//
#include <hip/hip_runtime.h>
#include <hip/hip_bf16.h>
#include <math.h>

// ---------- types ----------
typedef __attribute__((ext_vector_type(8)))  __bf16 bfrag;   // MFMA A/B operand (8 bf16)
typedef __attribute__((ext_vector_type(4)))  float  f32x4;
typedef __attribute__((ext_vector_type(16))) float  f32x16;  // 32x32 MFMA C/D
typedef __attribute__((ext_vector_type(8)))  short  s16x8;
typedef __attribute__((ext_vector_type(4)))  short  s16x4;
typedef __attribute__((ext_vector_type(2)))  unsigned u32x2;
typedef __attribute__((ext_vector_type(4)))  unsigned u32x4;

__device__ __forceinline__ short f2bf(float f) {
  return (short)__builtin_bit_cast(unsigned short, (__bf16)f);
}
__device__ __forceinline__ float bf2f(short s) {
  return (float)__builtin_bit_cast(__bf16, (unsigned short)s);
}
__device__ __forceinline__ unsigned cvtpk(float lo, float hi_) {
  unsigned r;
  asm("v_cvt_pk_bf16_f32 %0, %1, %2" : "=v"(r) : "v"(lo), "v"(hi_));
  return r;
}
__device__ __forceinline__ void gll16(const void* g, void* l) {
  __builtin_amdgcn_global_load_lds((const __attribute__((address_space(1))) void*)g,
                                   (__attribute__((address_space(3))) void*)l, 16, 0, 0);
}

// ---------- f32 -> bf16 converts (nontemporal input reads: read-once data) ----------
__global__ __launch_bounds__(256) void cvt_f32_bf16(const float* __restrict__ in,
                                                    short* __restrict__ out, int n4) {
  int i = blockIdx.x * 256 + threadIdx.x;
  if (i >= n4) return;
  f32x4 v = __builtin_nontemporal_load((const f32x4*)in + i);
  s16x4 o;
  o.x = f2bf(v.x); o.y = f2bf(v.y); o.z = f2bf(v.z); o.w = f2bf(v.w);
  ((s16x4*)out)[i] = o;
}

__global__ __launch_bounds__(256) void cvt4(const float* __restrict__ x,
                                            const float* __restrict__ wq,
                                            const float* __restrict__ wk,
                                            const float* __restrict__ wv,
                                            short* __restrict__ xb,
                                            short* __restrict__ wqb,
                                            short* __restrict__ wkb,
                                            short* __restrict__ wvb) {
  const int b = blockIdx.x;
  const float* in; short* out; int base;
  if (b < 16384)      { in = x;  out = xb;  base = 0; }
  else if (b < 32768) { in = wq; out = wqb; base = 16384 * 256; }
  else if (b < 36864) { in = wk; out = wkb; base = 32768 * 256; }
  else                { in = wv; out = wvb; base = 36864 * 256; }
  const int idx = b * 256 + threadIdx.x - base;
  f32x4 v = __builtin_nontemporal_load((const f32x4*)in + idx);
  s16x4 o;
  o.x = f2bf(v.x); o.y = f2bf(v.y); o.z = f2bf(v.z); o.w = f2bf(v.w);
  ((s16x4*)out)[idx] = o;
}

// ---------- interleaved (cos,sin) table: cs[sp*64+i] = {fcos, fsin} ----------
__global__ __launch_bounds__(256) void mkcs(const float* __restrict__ fc,
                                            const float* __restrict__ fs,
                                            float2* __restrict__ cs) {
  const int i = blockIdx.x * 256 + threadIdx.x;   // 131072 total
  cs[i] = make_float2(fc[i], fs[i]);
}

// ---------- shared staging macro (half-tile = 128 rows x 64 cols, 2 gll16/thr) ----------
#define STG_(OP, OPs, boff, bb, hh, kt_, Kd)                                     \
  do {                                                                           \
    _Pragma("unroll")                                                            \
    for (int s = 0; s < 2; ++s)                                                  \
      gll16(OP + (size_t)(boff + (hh) * 128 + s * 64 + r0) * Kd + (kt_) * 64 + csrc * 8, \
            (char*)OPs[bb] + ((hh) * 128 + s * 64 + wid * 8) * 128);             \
  } while (0)

// ---------- GEMM 128x256 (KV part; 256 blocks) + fused K-RoPE + fused V-transpose ----------
template<bool ROPE>
__global__ __launch_bounds__(512) void gemm128n(const short* __restrict__ A,
                                                const short* __restrict__ B,
                                                short* __restrict__ C,
                                                short* __restrict__ vt,
                                                int M, int N, int K, int NBX, int vstart,
                                                const float2* __restrict__ cst) {
  __shared__ __align__(16) short As[2][128 * 64];
  __shared__ __align__(16) short Bs[2][256 * 64];
  const int tid = threadIdx.x, lane = tid & 63, wid = tid >> 6;
  const int lr = lane & 15, lg = lane >> 4;
  const int wm = wid >> 2, wn = wid & 3;
  const int orig = blockIdx.x;
  const int xc = orig & 7, o8 = orig >> 3;
  const int s8 = o8 >> 5, t8 = o8 & 31;
  const int bmi = ((xc >> 1) << 3) + (t8 >> 2);
  const int bni = (xc & 1) * (NBX >> 1) + (s8 << 2) + (t8 & 3);
  const int bm = bmi << 7, bn = bni << 8;
  const int NT = K >> 6;
  const int r0 = tid >> 3;
  const int c0 = tid & 7;
  const int csrc = c0 ^ (r0 & 7);

  int ch[2];
#pragma unroll
  for (int ks = 0; ks < 2; ++ks) ch[ks] = (((ks << 2) | lg) ^ (lr & 7)) << 4;
  const int aoff  = (wm * 64 + lr) * 128;
  const int boff2 = (wn * 32 + lr) * 128;

#define RD_A(dst, bb)                                                            \
  do {                                                                           \
    const char* ab = (const char*)As[bb] + aoff;                                 \
    _Pragma("unroll") for (int i = 0; i < 4; ++i)                                \
      _Pragma("unroll") for (int ks = 0; ks < 2; ++ks)                           \
        dst[i][ks] = *(const bfrag*)(ab + i * 2048 + ch[ks]);                    \
  } while (0)
#define RD_B(dst, bb, jh)                                                        \
  do {                                                                           \
    const char* bp = (const char*)Bs[bb] + boff2 + (jh) * 16384;                 \
    _Pragma("unroll") for (int j = 0; j < 2; ++j)                                \
      _Pragma("unroll") for (int ks = 0; ks < 2; ++ks)                           \
        dst[j][ks] = *(const bfrag*)(bp + j * 2048 + ch[ks]);                    \
  } while (0)
#define MFMA16(af, bf, jh)                                                       \
  do {                                                                           \
    __builtin_amdgcn_s_setprio(1);                                               \
    _Pragma("unroll") for (int ks = 0; ks < 2; ++ks)                             \
      _Pragma("unroll") for (int i = 0; i < 4; ++i)                              \
        _Pragma("unroll") for (int j = 0; j < 2; ++j)                            \
          acc[i][(jh) * 2 + j] = __builtin_amdgcn_mfma_f32_16x16x32_bf16(        \
              af[i][ks], bf[j][ks], acc[i][(jh) * 2 + j], 0, 0, 0);              \
    __builtin_amdgcn_s_setprio(0);                                               \
  } while (0)

  STG_(A, As, bm, 0, 0, 0, K);
  STG_(B, Bs, bn, 0, 0, 0, K);
  STG_(B, Bs, bn, 0, 1, 0, K);
  if (NT > 1) {
    STG_(A, As, bm, 1, 0, 1, K);
    STG_(B, Bs, bn, 1, 0, 1, K);
    asm volatile("s_waitcnt vmcnt(4)" ::: "memory");
  } else {
    asm volatile("s_waitcnt vmcnt(0)" ::: "memory");
  }
  __builtin_amdgcn_s_barrier();
  __builtin_amdgcn_sched_barrier(0);

  f32x4 acc[4][4] = {};
  bfrag a_[4][2], b_lo[2][2], b_hi[2][2];

  for (int kt = 0; kt < NT; ++kt) {
    const int b = kt & 1;
    RD_A(a_, b);
    RD_B(b_lo, b, 0);
    if (kt + 1 < NT) STG_(B, Bs, bn, b ^ 1, 1, kt + 1, K);
    MFMA16(a_, b_lo, 0);
    __builtin_amdgcn_s_barrier();
    __builtin_amdgcn_sched_barrier(0);
    RD_B(b_hi, b, 1);
    if (kt + 2 < NT) {
      STG_(A, As, bm, b, 0, kt + 2, K);
      STG_(B, Bs, bn, b, 0, kt + 2, K);
    }
    MFMA16(a_, b_hi, 1);
    if (kt + 1 < NT) {
      if (kt + 2 < NT) asm volatile("s_waitcnt vmcnt(4)" ::: "memory");
      else             asm volatile("s_waitcnt vmcnt(0)" ::: "memory");
      __builtin_amdgcn_s_barrier();
      __builtin_amdgcn_sched_barrier(0);
    }
  }
#undef RD_A
#undef RD_B
#undef MFMA16
  // ---- epilogue: K-RoPE | transposed-V | plain ----
  const int rb = bm + wm * 64 + lg * 4, cb = bn + wn * 32 + lr;
  if (ROPE && bn < vstart) {
    const bool odd = (lr & 1) != 0;
#pragma unroll
    for (int j = 0; j < 2; ++j) {
      const int iidx = (wn * 32 + j * 16 + lr) >> 1;
#pragma unroll
      for (int i = 0; i < 4; ++i)
#pragma unroll
        for (int r = 0; r < 4; ++r) {
          const int row = rb + i * 16 + r;
          const int sp = row & 2047;
          const float2 cs = cst[sp * 64 + iidx];
#pragma unroll
          for (int jh = 0; jh < 2; ++jh) {
            float own = acc[i][jh * 2 + j][r];
            float par = __shfl_xor(own, 1, 64);
            float out = odd ? (par * cs.y + own * cs.x) : (own * cs.x - par * cs.y);
            C[(size_t)row * N + (cb + jh * 128 + j * 16)] = f2bf(out);
          }
        }
    }
  } else if (ROPE) {
#pragma unroll
    for (int jh = 0; jh < 2; ++jh)
#pragma unroll
      for (int j = 0; j < 2; ++j) {
        const int vcol = cb + jh * 128 + j * 16 - vstart;  // 0..1023
        const int kvh = vcol >> 7, d = vcol & 127;
#pragma unroll
        for (int i = 0; i < 4; ++i) {
          const int row0 = rb + i * 16;                    // 4 consecutive tokens
          const int bb = row0 >> 11, s0 = row0 & 2047;
          s16x4 v;
#pragma unroll
          for (int r = 0; r < 4; ++r) v[r] = f2bf(acc[i][jh * 2 + j][r]);
          *(s16x4*)(vt + (size_t)((bb * 8 + kvh) * 128 + d) * 2048 + s0) = v;
        }
      }
  } else {
#pragma unroll
    for (int i = 0; i < 4; ++i)
#pragma unroll
      for (int jh = 0; jh < 2; ++jh)
#pragma unroll
        for (int j = 0; j < 2; ++j)
#pragma unroll
          for (int r = 0; r < 4; ++r)
            C[(size_t)(rb + i * 16 + r) * N + (cb + jh * 128 + j * 16)] =
                f2bf(acc[i][jh * 2 + j][r]);
  }
}

// ---------- GEMM 256x256, BK=64, m201 8-phase (256 blocks = 1 round) ----------
// OMODE 0: f32 plain out (out-proj). OMODE 1: bf16 out + fused Q-RoPE.
template<int OMODE>
__global__ __launch_bounds__(512) void gemm256p(const short* __restrict__ A,
                                                const short* __restrict__ B,
                                                void* __restrict__ Cv,
                                                int M, int N, int K, int NBX,
                                                const float2* __restrict__ cst) {
  __shared__ __align__(16) short As[2][256 * 64];   // 64 KB
  __shared__ __align__(16) short Bs[2][256 * 64];   // 64 KB
  const int tid = threadIdx.x, lane = tid & 63, wid = tid >> 6;
  const int lr = lane & 15, lg = lane >> 4;
  const int wm = wid >> 2, wn = wid & 3;
  const int orig = blockIdx.x;
  const int xc = orig & 7, o8 = orig >> 3;
  const int bmi = ((xc >> 1) << 2) + (o8 & 3);
  const int bni = (xc & 1) * (NBX >> 1) + (o8 >> 2);
  const int bm = bmi << 8, bn = bni << 8;
  const int NT = K >> 6;
  const int r0 = tid >> 3;
  const int c0 = tid & 7;
  const int csrc = c0 ^ (r0 & 7);

  int ch[2];
#pragma unroll
  for (int ks = 0; ks < 2; ++ks) ch[ks] = (((ks << 2) | lg) ^ (lr & 7)) << 4;
  const int aoff = (wm * 128 + lr) * 128;
  const int boff = (wn * 64 + lr) * 128;

#define RD_A8(dst, bb, ih)                                                       \
  do {                                                                           \
    const char* ab = (const char*)As[bb] + aoff + (ih) * 8192;                   \
    _Pragma("unroll") for (int i = 0; i < 4; ++i)                                \
      _Pragma("unroll") for (int ks = 0; ks < 2; ++ks)                           \
        dst[i][ks] = *(const bfrag*)(ab + i * 2048 + ch[ks]);                    \
  } while (0)
#define RD_B4(dst, bb, jh)                                                       \
  do {                                                                           \
    const char* bp = (const char*)Bs[bb] + boff + (jh) * 4096;                   \
    _Pragma("unroll") for (int j = 0; j < 2; ++j)                                \
      _Pragma("unroll") for (int ks = 0; ks < 2; ++ks)                           \
        dst[j][ks] = *(const bfrag*)(bp + j * 2048 + ch[ks]);                    \
  } while (0)
#define QUAD(af, bf, ih, jh)                                                     \
  do {                                                                           \
    __builtin_amdgcn_s_setprio(1);                                               \
    _Pragma("unroll") for (int ks = 0; ks < 2; ++ks)                             \
      _Pragma("unroll") for (int i = 0; i < 4; ++i)                              \
        _Pragma("unroll") for (int j = 0; j < 2; ++j)                            \
          acc[(ih) * 4 + i][(jh) * 2 + j] = __builtin_amdgcn_mfma_f32_16x16x32_bf16( \
              af[i][ks], bf[j][ks], acc[(ih) * 4 + i][(jh) * 2 + j], 0, 0, 0);   \
    __builtin_amdgcn_s_setprio(0);                                               \
  } while (0)
#define BARRIER() do { __builtin_amdgcn_s_barrier(); __builtin_amdgcn_sched_barrier(0); } while (0)

  STG_(A, As, bm, 0, 0, 0, K); STG_(A, As, bm, 0, 1, 0, K);
  STG_(B, Bs, bn, 0, 0, 0, K); STG_(B, Bs, bn, 0, 1, 0, K);
  STG_(B, Bs, bn, 1, 0, 1, K); STG_(B, Bs, bn, 1, 1, 1, K);
  asm volatile("s_waitcnt vmcnt(4)" ::: "memory");
  BARRIER();

  f32x4 acc[8][4] = {};
  bfrag a_[4][2], b_lo[2][2], b_hi[2][2];
  const int NI = NT >> 1;

  for (int it = 0; it < NI; ++it) {
    const int O  = 2 * it + 1;
    int E2 = 2 * it + 2; if (E2 >= NT) E2 = 0;
    int O2 = 2 * it + 3; if (O2 >= NT) O2 = 0;
    RD_A8(a_, 0, 0);
    RD_B4(b_lo, 0, 0);
    STG_(A, As, bm, 1, 0, O, K);
    BARRIER();
    asm volatile("s_waitcnt lgkmcnt(0)" ::: "memory");
    QUAD(a_, b_lo, 0, 0);
    BARRIER();
    RD_B4(b_hi, 0, 1);
    STG_(A, As, bm, 1, 1, O, K);
    BARRIER();
    asm volatile("s_waitcnt lgkmcnt(0)" ::: "memory");
    QUAD(a_, b_hi, 0, 1);
    BARRIER();
    RD_A8(a_, 0, 1);
    STG_(B, Bs, bn, 0, 0, E2, K);
    BARRIER();
    asm volatile("s_waitcnt lgkmcnt(0)" ::: "memory");
    QUAD(a_, b_hi, 1, 1);
    BARRIER();
    STG_(B, Bs, bn, 0, 1, E2, K);
    asm volatile("s_waitcnt vmcnt(4)" ::: "memory");
    BARRIER();
    QUAD(a_, b_lo, 1, 0);
    BARRIER();
    RD_A8(a_, 1, 0);
    RD_B4(b_lo, 1, 0);
    STG_(A, As, bm, 0, 0, E2, K);
    BARRIER();
    asm volatile("s_waitcnt lgkmcnt(0)" ::: "memory");
    QUAD(a_, b_lo, 0, 0);
    BARRIER();
    RD_B4(b_hi, 1, 1);
    STG_(A, As, bm, 0, 1, E2, K);
    BARRIER();
    asm volatile("s_waitcnt lgkmcnt(0)" ::: "memory");
    QUAD(a_, b_hi, 0, 1);
    BARRIER();
    RD_A8(a_, 1, 1);
    STG_(B, Bs, bn, 1, 0, O2, K);
    BARRIER();
    asm volatile("s_waitcnt lgkmcnt(0)" ::: "memory");
    QUAD(a_, b_hi, 1, 1);
    BARRIER();
    STG_(B, Bs, bn, 1, 1, O2, K);
    asm volatile("s_waitcnt vmcnt(4)" ::: "memory");
    BARRIER();
    QUAD(a_, b_lo, 1, 0);
    BARRIER();
  }
#undef RD_A8
#undef RD_B4
#undef QUAD
#undef BARRIER
  // ---- epilogue ----
  const int rb = bm + wm * 128 + lg * 4, cb = bn + wn * 64 + lr;
  if (OMODE == 1) {
    const bool odd = (lr & 1) != 0;
#pragma unroll
    for (int j = 0; j < 4; ++j) {
      const int iidx = ((wn * 64 + j * 16 + lr) & 127) >> 1;
#pragma unroll
      for (int i = 0; i < 8; ++i)
#pragma unroll
        for (int r = 0; r < 4; ++r) {
          const int row = rb + i * 16 + r;
          const int sp = row & 2047;
          const float2 cs = cst[sp * 64 + iidx];
          float own = acc[i][j][r];
          float par = __shfl_xor(own, 1, 64);
          float out = odd ? (par * cs.y + own * cs.x) : (own * cs.x - par * cs.y);
          ((short*)Cv)[(size_t)row * N + (cb + j * 16)] = f2bf(out);
        }
    }
  } else {
#pragma unroll
    for (int i = 0; i < 8; ++i)
#pragma unroll
      for (int j = 0; j < 4; ++j)
#pragma unroll
        for (int r = 0; r < 4; ++r)
          ((float*)Cv)[(size_t)(rb + i * 16 + r) * N + (cb + j * 16)] = acc[i][j][r];
  }
}

// ---------- Flash attention, m214 structure; qb<->z balance flip ----------
__global__ __launch_bounds__(512, 2) void fattn2(const short* __restrict__ qkv,
                                                 const short* __restrict__ vt,
                                                 short* __restrict__ ao) {
  const int b = blockIdx.z, h = blockIdx.y;
  const int qb = b ? (int)gridDim.x - 1 - blockIdx.x : blockIdx.x;
  const int kvh = h >> 2;
  const int tid = threadIdx.x;
  const int lane = tid & 63, wid = tid >> 6;
  const int l31 = lane & 31, hi = lane >> 5;
  __shared__ __align__(16) short Ks[2][64 * 128];
  __shared__ __align__(16) short Vs[2][128 * 64];

  const int q0w   = qb * 256 + wid * 32;
  const int qg    = q0w + l31;
  const int tmaxw = q0w >> 6;
  const int NT    = 4 * qb + 4;

  bfrag qf[8];
  {
    const short* qp = qkv + (size_t)(b * 2048 + qg) * 6144 + h * 128 + hi * 8;
#pragma unroll
    for (int kk = 0; kk < 8; ++kk) qf[kk] = *(const bfrag*)(qp + kk * 16);
  }

  const int kr0 = tid >> 4, kcc = tid & 15;
  const int vd0 = tid >> 3, vkc = tid & 7;
  const int kro[2] = { kr0, kr0 + 32 };
  const int vdo[2] = { vd0, vd0 + 64 };
  int kldst[2], vldst[2];
#pragma unroll
  for (int i = 0; i < 2; ++i) {
    kldst[i] = (kro[i] * 256 + kcc * 16) ^ ((kro[i] & 7) << 4);
    vldst[i] = (vdo[i] * 128 + vkc * 16) ^ ((vdo[i] & 7) << 4);
  }
  const short* base_k = qkv + (size_t)(b * 2048) * 6144 + 4096 + kvh * 128;
  const short* base_v = vt + (size_t)((b * 8 + kvh) * 128) * 2048;

  {
    s16x8 kr_[2], vr_[2];
#pragma unroll
    for (int i = 0; i < 2; ++i) {
      kr_[i] = *(const s16x8*)(base_k + (size_t)kro[i] * 6144 + kcc * 8);
      vr_[i] = *(const s16x8*)(base_v + (size_t)vdo[i] * 2048 + vkc * 8);
    }
#pragma unroll
    for (int i = 0; i < 2; ++i) {
      *(s16x8*)((char*)Ks[0] + kldst[i]) = kr_[i];
      *(s16x8*)((char*)Vs[0] + vldst[i]) = vr_[i];
    }
  }
  __syncthreads();

  f32x16 o[4] = {};
  float m = -3.0e38f, l = 0.f;
  const float c0 = 0.08838834764831845f * 1.4426950408889634f;
  const int  sw = (l31 & 7) << 4;

  for (int t = 0; t < NT; ++t) {
    const int cur = t & 1;
    s16x8 kr_[2], vr_[2];
    const bool pf = (t + 1 < NT);
    if (pf) {
#pragma unroll
      for (int i = 0; i < 2; ++i) {
        kr_[i] = *(const s16x8*)(base_k + (size_t)((t + 1) * 64 + kro[i]) * 6144 + kcc * 8);
        vr_[i] = *(const s16x8*)(base_v + (size_t)vdo[i] * 2048 + (t + 1) * 64 + vkc * 8);
      }
    }
    if (t <= tmaxw) {
      f32x16 st[2] = {};
      {
        const char* kb = (const char*)Ks[cur] + l31 * 256;
        __builtin_amdgcn_s_setprio(1);
#pragma unroll
        for (int kk = 0; kk < 8; ++kk) {
          const int ko = (kk * 32 + hi * 16) ^ sw;
          bfrag kf0 = *(const bfrag*)(kb + ko);
          bfrag kf1 = *(const bfrag*)(kb + 8192 + ko);
          st[0] = __builtin_amdgcn_mfma_f32_32x32x16_bf16(kf0, qf[kk], st[0], 0, 0, 0);
          st[1] = __builtin_amdgcn_mfma_f32_32x32x16_bf16(kf1, qf[kk], st[1], 0, 0, 0);
        }
        __builtin_amdgcn_s_setprio(0);
      }
      if (t == tmaxw) {
        const int kb0 = t * 64 + 4 * hi;
#pragma unroll
        for (int kt = 0; kt < 2; ++kt)
#pragma unroll
          for (int r = 0; r < 16; ++r) {
            int k = kb0 + kt * 32 + (r & 3) + 8 * (r >> 2);
            if (k > qg) st[kt][r] = -3.0e38f;
          }
      }
      float mt = -3.0e38f;
#pragma unroll
      for (int kt = 0; kt < 2; ++kt)
#pragma unroll
        for (int r = 0; r < 16; ++r) mt = fmaxf(mt, st[kt][r]);
      mt = fmaxf(mt, __shfl_xor(mt, 32, 64));
      if (!__all((mt - m) * c0 <= 8.0f)) {
        float nm = fmaxf(m, mt);
        float fe = exp2f((m - nm) * c0);
        m = nm;
        l *= fe;
#pragma unroll
        for (int dt = 0; dt < 4; ++dt)
#pragma unroll
          for (int r = 0; r < 16; ++r) o[dt][r] *= fe;
      }
      const float mc = m * c0;
      float ps = 0.f;
#pragma unroll
      for (int kt = 0; kt < 2; ++kt)
#pragma unroll
        for (int r = 0; r < 16; ++r) {
          float p = exp2f(st[kt][r] * c0 - mc);
          st[kt][r] = p;
          ps += p;
        }
      ps += __shfl_xor(ps, 32, 64);
      l += ps;
      bfrag pfr[4];
#pragma unroll
      for (int kt = 0; kt < 2; ++kt) {
        u32x2 a0 = __builtin_amdgcn_permlane32_swap(cvtpk(st[kt][0],  st[kt][1]),
                                                    cvtpk(st[kt][4],  st[kt][5]),  0, 0);
        u32x2 a1 = __builtin_amdgcn_permlane32_swap(cvtpk(st[kt][2],  st[kt][3]),
                                                    cvtpk(st[kt][6],  st[kt][7]),  0, 0);
        u32x2 b0 = __builtin_amdgcn_permlane32_swap(cvtpk(st[kt][8],  st[kt][9]),
                                                    cvtpk(st[kt][12], st[kt][13]), 0, 0);
        u32x2 b1 = __builtin_amdgcn_permlane32_swap(cvtpk(st[kt][10], st[kt][11]),
                                                    cvtpk(st[kt][14], st[kt][15]), 0, 0);
        u32x4 w0 = { a0.x, a1.x, a0.y, a1.y };
        u32x4 w1 = { b0.x, b1.x, b0.y, b1.y };
        pfr[kt * 2]     = __builtin_bit_cast(bfrag, w0);
        pfr[kt * 2 + 1] = __builtin_bit_cast(bfrag, w1);
      }
      __builtin_amdgcn_s_setprio(1);
#pragma unroll
      for (int ks = 0; ks < 4; ++ks) {
        const char* vb = (const char*)Vs[cur] + l31 * 128 + ((ks * 32 + hi * 16) ^ sw);
#pragma unroll
        for (int dt = 0; dt < 4; ++dt) {
          bfrag vf = *(const bfrag*)(vb + dt * 4096);
          o[dt] = __builtin_amdgcn_mfma_f32_32x32x16_bf16(vf, pfr[ks], o[dt], 0, 0, 0);
        }
      }
      __builtin_amdgcn_s_setprio(0);
    }
    __syncthreads();
    if (pf) {
#pragma unroll
      for (int i = 0; i < 2; ++i) {
        *(s16x8*)((char*)Ks[cur ^ 1] + kldst[i]) = kr_[i];
        *(s16x8*)((char*)Vs[cur ^ 1] + vldst[i]) = vr_[i];
      }
    }
    __syncthreads();
  }
  const float linv = 1.f / l;
  short* aop = ao + (size_t)(b * 2048 + qg) * 4096 + h * 128 + 4 * hi;
#pragma unroll
  for (int dt = 0; dt < 4; ++dt)
#pragma unroll
    for (int r = 0; r < 16; ++r) {
      int d = dt * 32 + (r & 3) + 8 * (r >> 2);
      aop[d] = f2bf(o[dt][r] * linv);
    }
}

// ---------- launch ----------
extern "C" void kernel_launch(void* const* d_in, const int* in_sizes, int n_in,
                              void* d_out, int out_size, void* d_ws, size_t ws_size,
                              hipStream_t stream) {
  const float* x  = (const float*)d_in[0];
  const float* wq = (const float*)d_in[1];
  const float* wk = (const float*)d_in[2];
  const float* wv = (const float*)d_in[3];
  const float* wo = (const float*)d_in[4];
  const float* fc = (const float*)d_in[7];
  const float* fs = (const float*)d_in[8];

  char* ws = (char*)d_ws;
  short* xb    = (short*)(ws);                    // [4096][4096] bf16; reused as ao
  short* ao    = xb;
  short* wqkvb = (short*)(ws + 33554432ull);      // [6144][4096] bf16
  short* qkv   = (short*)(ws + 83886080ull);      // [4096][6144] bf16 (V region unused)
  short* vt    = (short*)(ws + 134217728ull);     // [2][8][128][2048] bf16
  short* wob   = (short*)(ws + 167772160ull);     // [4096][4096] bf16
  float2* cst  = (float2*)wob;                    // 1 MB; dead before cvt_wo writes wob

  cvt4<<<40960, 256, 0, stream>>>(x, wq, wk, wv,
                                  xb, wqkvb, wqkvb + 16777216, wqkvb + 20971520);
  mkcs<<<512, 256, 0, stream>>>(fc, fs, cst);
  // QKV split: Q part (N=4096) on the 256^2 8-phase kernel, 1 exact round;
  // K|V part (N=2048) on the 128x256 kernel, 1 exact round.
  gemm256p<1><<<256, 512, 0, stream>>>(xb, wqkvb, qkv, 4096, 6144, 4096, 16, cst);
  gemm128n<true><<<256, 512, 0, stream>>>(xb, wqkvb + 16777216ull, qkv + 4096, vt,
                                          4096, 6144, 4096, 8, 1024, cst);
  cvt_f32_bf16<<<16384, 256, 0, stream>>>(wo, wob, 4194304);
  fattn2<<<dim3(8, 32, 2), 512, 0, stream>>>(qkv, vt, ao);
  gemm256p<0><<<256, 512, 0, stream>>>(ao, wob, (float*)d_out, 4096, 4096, 4096, 16,
                                       nullptr);
}